// Round 6
// baseline (220.190 us; speedup 1.0000x reference)
//
#include <hip/hip_runtime.h>

// B=16, L=2048, V=64.
// Algebraic reduction (e is one-hot):
//   E[d] = exp(v_emb[d]); S[t] = prefix_sum(E)[t]
//   F[b,c,s] = sum_{k<=s} E[s-k] * Wq[idx[b,k], c]            (causal Toeplitz GEMM)
//   P[b,c,s] = exp(F[b,c,s] / S[s])                           (softmax w/o max; scores tiny)
//   out[b,t,v] = Wv00 * (sum_{s<=t, idx[b,s]==v} P[b,c_t,s]) / (sum_{s<=t} P[b,c_t,s]),  c_t = idx[b,t]
//
// R21: four sync mechanisms all land at ~90-100us -> the cost is IN the
// phases, not the barriers. Two mechanisms: (1) occupancy starvation —
// (256,2) x 512 blocks = 8 waves/CU (Occ 20%) on latency-bound phases; the
// 3-kernel path ran ~9 blocks/CU. (2) per-emission __threadfence_block
// pairs = s_waitcnt vmcnt(0) draining each scattered out-store (~64 x
// ~800cyc ~= 20-25us/block-serial). Fix: grid 1024 @ (256,4) -> 4 blocks/CU
// 16 waves/CU, per-block work halved everywhere (1 GEMM tile/block heavy-
// first, 4 k8/block gather, 1 (b,c)/block emit); emission rewritten
// fence-free via per-bin lane bitmasks + shfl prefix (no LDS atomics, no
// fences, fire-and-forget stores). prepFlag replicated x64 lines.
// Predicted k_fused 100 -> 40-60us.

#define LSEQ 2048
#define NB 16
#define NV 64
#define NC 32             // 32 chunks of 64
#define NBLK 1024         // fused grid size
#define BPB 64            // blocks per batch

typedef __attribute__((ext_vector_type(8))) short bf16x8;
typedef __attribute__((ext_vector_type(4))) float f32x4;

__device__ __forceinline__ unsigned short f2bf(float f) {   // RNE float->bf16
  unsigned int u = __float_as_uint(f);
  return (unsigned short)((u + 0x7FFFu + ((u >> 16) & 1u)) >> 16);
}

// ---- per-batch barrier (BPB participants), arrive/wait split -------------
__device__ __forceinline__ void bb_arrive(unsigned int* cnt, unsigned int* flag) {
  __syncthreads();                      // all block work done
  if (threadIdx.x == 0) {
    unsigned int old = __hip_atomic_fetch_add(cnt, 1u, __ATOMIC_ACQ_REL,
                                              __HIP_MEMORY_SCOPE_AGENT);
    if (old == BPB - 1u)                // last arriver releases the batch
      __hip_atomic_store(flag, 1u, __ATOMIC_RELEASE, __HIP_MEMORY_SCOPE_AGENT);
  }
}
__device__ __forceinline__ void bb_wait(unsigned int* flag) {
  if (threadIdx.x == 0) {
    while (__hip_atomic_load(flag, __ATOMIC_RELAXED,
                             __HIP_MEMORY_SCOPE_AGENT) == 0u)
      __builtin_amdgcn_s_sleep(2);      // line-local read-only poll
    __builtin_amdgcn_fence(__ATOMIC_ACQUIRE, "agent");
  }
  __syncthreads();
}

// =====================================================================
// Fused kernel, grid=1024: phase0 gather+prep | batchbar | phase1 GEMM
// (1 tile/block) | batchbar | phase2 scan+emit (1 (b,c)/block).
// =====================================================================
__global__ __launch_bounds__(256, 4) void k_fused(
    const int* __restrict__ idx, const float* __restrict__ Wq,
    const float* __restrict__ Wv, const float* __restrict__ v_emb,
    unsigned short* __restrict__ Agr, unsigned short* __restrict__ Ebf,
    float* __restrict__ S, float* __restrict__ P, float* __restrict__ out,
    unsigned int* __restrict__ bar) {
  union SMem {
    struct {  // phase 1 (GEMM)
      unsigned short GL0[2208];   // GL0[i] = (127<=i<2175) ? E[i-127] : 0
      unsigned short GL1[2176];   // GL1[i] = GLv(i+1)
      float red[16][64];
      float red2[16][64];
    } g;
    struct {  // phase 2 (scan+emit)
      float Hs[NC][65];
      float pl[4][64];
      unsigned long long mk[4][64];
    } s;
  };
  __shared__ SMem sm;

  const int bid = blockIdx.x;     // [0, 1024)
  const int tid = threadIdx.x;
  const int w = tid >> 6;
  const int lane = tid & 63;
  const int b = bid >> 6;         // this block's batch, ALL phases

  // sync layout in bar (uints; 32 uints = 128B line each):
  // prepFlagArr[64] @0 | cnt0[b] @2048+b*32 | flag0[b] @2560+b*32
  // cnt1[b] @3072+b*32 | flag1[b] @3584+b*32       (total 4096 uints = 16KB)
  unsigned int* prepFlagMine = bar + (bid & 63) * 32;
  unsigned int* cnt0b  = bar + 2048 + b * 32;
  unsigned int* flag0b = bar + 2560 + b * 32;
  unsigned int* cnt1b  = bar + 3072 + b * 32;
  unsigned int* flag1b = bar + 3584 + b * 32;

  // ---------------- phase 0: prep (1 wave) + gather -------------------
  {
    const int sub = bid & 63;

    if (bid == 0 && tid < 64) {   // fused prep (one wave)
      const int base = lane * 32;
      float e[32];
      float run = 0.f;
#pragma unroll
      for (int i = 0; i < 32; ++i) { e[i] = expf(v_emb[base + i]); run += e[i]; }
      float incl = run;
#pragma unroll
      for (int d = 1; d < 64; d <<= 1) {
        float up = __shfl_up(incl, d);
        if (lane >= d) incl += up;
      }
      float acc = incl - run;
#pragma unroll
      for (int i = 0; i < 32; ++i) {
        acc += e[i];
        Ebf[base + i] = f2bf(e[i]);
        S[base + i] = acc;
      }
      // release store waits the WAVE's vmcnt -> covers all 64 lanes' stores;
      // each lane releases one replicated flag line (64 lines, no poll pileup)
      __hip_atomic_store(bar + lane * 32, 1u, __ATOMIC_RELEASE,
                         __HIP_MEMORY_SCOPE_AGENT);
    }

    // 1 k8-group per wave (4 per block)
    const int k8 = sub * 4 + w;
    unsigned short v[8];
#pragma unroll
    for (int j = 0; j < 8; ++j) {
      const int ii = idx[b * LSEQ + (2047 - (k8 * 8 + j))];  // wave-uniform
      v[j] = f2bf(Wq[ii * 64 + lane]);                       // coalesced row read
    }
    uint4 st;
    st.x = (unsigned int)v[0] | ((unsigned int)v[1] << 16);
    st.y = (unsigned int)v[2] | ((unsigned int)v[3] << 16);
    st.z = (unsigned int)v[4] | ((unsigned int)v[5] << 16);
    st.w = (unsigned int)v[6] | ((unsigned int)v[7] << 16);
    *(uint4*)(Agr + ((size_t)(b * 256 + k8) * 64 + lane) * 8) = st;
  }
  bb_arrive(cnt0b, flag0b);        // phase-0 done for this block

  // prep gate (Ebf/S): poll own replicated line, one acquire fence
  if (tid == 0) {
    while (__hip_atomic_load(prepFlagMine, __ATOMIC_RELAXED,
                             __HIP_MEMORY_SCOPE_AGENT) == 0u)
      __builtin_amdgcn_s_sleep(2);
    __builtin_amdgcn_fence(__ATOMIC_ACQUIRE, "agent");
  }
  __syncthreads();

  // ---------------- phase 1: MFMA GEMM, ONE tile per block ------------
  {
    const int bn = 63 - (bid & 63);          // heavy (long-K) blocks first
    const int n0 = bn * 32;
    const int quad = lane >> 4;
    const int lm = lane & 15;
    const int nsub = w & 1;                  // n-offset 0 / 16
    const int kh = w >> 1;                   // k-half 0 / 1
    const unsigned short* __restrict__ abase = Agr + (size_t)b * 256 * 64 * 8;

    // stage ONLY the window this tile reads: i in [96, n0+160)
    {
      const int wend = n0 + 160;
      for (int i = 96 + tid; i < wend; i += 256) {
        const int e0 = i - 127;
        const int e1 = i - 126;
        sm.g.GL0[i] = (e0 >= 0 && e0 < LSEQ) ? Ebf[e0] : (unsigned short)0;
        sm.g.GL1[i] = (e1 >= 0 && e1 < LSEQ) ? Ebf[e1] : (unsigned short)0;
      }
    }
    bb_wait(flag0b);   // Agr[b] complete; ends with __syncthreads (staging bar)

    f32x4 acc[4];
#pragma unroll
    for (int mt = 0; mt < 4; ++mt) acc[mt] = (f32x4){0.f, 0.f, 0.f, 0.f};

    const int nbase = n0 + nsub * 16;
    const int sbase = nbase + lm - 1920;
    const int kstart = 2048 - (n0 + 32);     // multiple of 32
    const int iters = bn + 1;                // total 32-k steps for this tile

    union AF { uint4 u; bf16x8 v; };
    union BF { unsigned int u[4]; bf16x8 v; };
    AF a[3][4];
    BF bb[3];

#define LOAD_FRAGS(J_, SL) do {                                             \
    const int k_ = kstart + (kh + 2 * (J_)) * 32;                           \
    const int kq8_ = (k_ >> 3) + quad;                                      \
    const unsigned short* ab_ = abase + ((size_t)kq8_ * 64 + lm) * 8;       \
    a[SL][0].u = *(const uint4*)(ab_ + 0 * 128);                            \
    a[SL][1].u = *(const uint4*)(ab_ + 1 * 128);                            \
    a[SL][2].u = *(const uint4*)(ab_ + 2 * 128);                            \
    a[SL][3].u = *(const uint4*)(ab_ + 3 * 128);                            \
    const int s_ = sbase + k_ + quad * 8;                                   \
    const unsigned int* gb_ = (s_ & 1) ? (const unsigned int*)sm.g.GL1      \
                                       : (const unsigned int*)sm.g.GL0;     \
    const int off_ = s_ >> 1;                                               \
    bb[SL].u[0] = gb_[off_ + 0]; bb[SL].u[1] = gb_[off_ + 1];               \
    bb[SL].u[2] = gb_[off_ + 2]; bb[SL].u[3] = gb_[off_ + 3];               \
  } while (0)

#define MFMA4(SL) do {                                                      \
    acc[0] = __builtin_amdgcn_mfma_f32_16x16x32_bf16(a[SL][0].v, bb[SL].v, acc[0], 0, 0, 0); \
    acc[1] = __builtin_amdgcn_mfma_f32_16x16x32_bf16(a[SL][1].v, bb[SL].v, acc[1], 0, 0, 0); \
    acc[2] = __builtin_amdgcn_mfma_f32_16x16x32_bf16(a[SL][2].v, bb[SL].v, acc[2], 0, 0, 0); \
    acc[3] = __builtin_amdgcn_mfma_f32_16x16x32_bf16(a[SL][3].v, bb[SL].v, acc[3], 0, 0, 0); \
  } while (0)

    const int J = (iters > kh) ? ((iters - kh + 1) >> 1) : 0;  // wave-iters
    if (J > 0) {
      LOAD_FRAGS(0, 0);
      if (J > 1) LOAD_FRAGS(1, 1);
      int j = 0;
      while (true) {
        if (j + 2 < J) LOAD_FRAGS(j + 2, 2);
        MFMA4(0);
        if (++j >= J) break;
        if (j + 2 < J) LOAD_FRAGS(j + 2, 0);
        MFMA4(1);
        if (++j >= J) break;
        if (j + 2 < J) LOAD_FRAGS(j + 2, 1);
        MFMA4(2);
        if (++j >= J) break;
      }
    }
#undef LOAD_FRAGS
#undef MFMA4

    // reduce k-half 1 into k-half 0 via LDS (lane-contiguous, conflict-free)
    if (kh == 1) {
      float (*rd)[64] = nsub ? sm.g.red2 : sm.g.red;
#pragma unroll
      for (int mt = 0; mt < 4; ++mt)
#pragma unroll
        for (int r = 0; r < 4; ++r) rd[mt * 4 + r][lane] = acc[mt][r];
    }
    __syncthreads();
    if (kh == 0) {
      float (*rd)[64] = nsub ? sm.g.red2 : sm.g.red;
#pragma unroll
      for (int mt = 0; mt < 4; ++mt)
#pragma unroll
        for (int r = 0; r < 4; ++r) acc[mt][r] += rd[mt * 4 + r][lane];

      // epilogue: C/D layout col(s)=lm, row(c)=quad*4+r
      const float sinv = 1.0f / S[nbase + lm];
#pragma unroll
      for (int mt = 0; mt < 4; ++mt) {
#pragma unroll
        for (int r = 0; r < 4; ++r) {
          const int c = mt * 16 + quad * 4 + r;
          P[((size_t)(b * 64 + c)) * LSEQ + nbase + lm] = __expf(acc[mt][r] * sinv);
        }
      }
    }
  }
  bb_arrive(cnt1b, flag1b);        // P[b] columns from this block complete

  // ---------------- phase 2: chunk-hists + scan + fence-free emission --
  {
    const int c = bid & 63;        // this block's vocab bin; bc = bid
    const int* __restrict__ irow = idx + b * LSEQ;
    int ii[8];
#pragma unroll
    for (int r = 0; r < 8; ++r)    // idx-only loads: overlap the wait
      ii[r] = irow[(w * 8 + r) * 64 + lane];

    bb_wait(flag1b);               // all of batch b's P rows ready

    const float* __restrict__ prow = P + (size_t)bid * LSEQ;
    float p[8];
#pragma unroll
    for (int r = 0; r < 8; ++r)
      p[r] = prow[(w * 8 + r) * 64 + lane];

    for (int i = tid; i < NC * 65; i += 256) ((float*)sm.s.Hs)[i] = 0.f;
    __syncthreads();
#pragma unroll
    for (int r = 0; r < 8; ++r) atomicAdd(&sm.s.Hs[w * 8 + r][ii[r]], p[r]);
    __syncthreads();

    // exclusive scan across chunks, per bin: 2 bins per pass (lane halves)
    const int hhalf = lane >> 5, l32 = lane & 31;
#pragma unroll
    for (int r = 0; r < 8; ++r) {
      const int v = w * 16 + r * 2 + hhalf;
      const float h = sm.s.Hs[l32][v];
      float x = h;
#pragma unroll
      for (int d = 1; d < 32; d <<= 1) {
        float up = __shfl_up(x, d, 32);
        if (l32 >= d) x += up;
      }
      sm.s.Hs[l32][v] = x - h;     // exclusive
    }
    __syncthreads();

    const float wv = Wv[0];
#pragma unroll
    for (int r = 0; r < 8; ++r) {
      const int ch = w * 8 + r;
      unsigned long long em = __ballot(ii[r] == c);   // emission points
      if (em == 0ull) continue;                       // wave-uniform skip
      // per-chunk setup (wave-synchronous LDS, no fences):
      sm.s.pl[w][lane] = p[r];                        // stage p
      sm.s.mk[w][lane] = 0ull;
      atomicOr(&sm.s.mk[w][ii[r]], 1ull << lane);     // bin <- source lanes
      float ps = p[r];                                // within-chunk prefix
#pragma unroll
      for (int d = 1; d < 64; d <<= 1) {
        float up = __shfl_up(ps, d);
        if (lane >= d) ps += up;
      }
      const float hbase = sm.s.Hs[ch][lane];
      float zex = hbase;                              // Z_excl = sum_v Hs
#pragma unroll
      for (int d = 1; d < 64; d <<= 1) zex += __shfl_xor(zex, d);
      const unsigned long long myMask = sm.s.mk[w][lane];
      while (em) {
        const int srel = __builtin_ctzll(em);
        em &= em - 1;
        unsigned long long mm = myMask &
            ((srel == 63) ? ~0ull : ((1ull << (srel + 1)) - 1ull));
        float B = hbase;                              // bin value at this t
        while (mm) { const int l = __builtin_ctzll(mm); mm &= mm - 1; B += sm.s.pl[w][l]; }
        const float z = zex + __shfl(ps, srel);       // denominator
        out[((size_t)(b * LSEQ + ch * 64 + srel)) * 64 + lane] = wv * B / z;
      }
    }
  }
}

// =====================================================================
// Fallback path: the verified 3-kernel pipeline (R11), used only if the
// cooperative launch is rejected.
// =====================================================================
__global__ __launch_bounds__(256) void k_gather(const int* __restrict__ idx,
                                                const float* __restrict__ Wq,
                                                const float* __restrict__ v_emb,
                                                unsigned short* __restrict__ Agr,
                                                unsigned short* __restrict__ Ebf,
                                                float* __restrict__ S) {
  const int b = blockIdx.x >> 4;
  const int tile = blockIdx.x & 15;
  const int w = threadIdx.x >> 6;
  const int lane = threadIdx.x & 63;

  if (blockIdx.x == 0 && threadIdx.x < 64) {
    const int base = lane * 32;
    float e[32];
    float run = 0.f;
#pragma unroll
    for (int i = 0; i < 32; ++i) { e[i] = expf(v_emb[base + i]); run += e[i]; }
    float incl = run;
#pragma unroll
    for (int d = 1; d < 64; d <<= 1) {
      float up = __shfl_up(incl, d);
      if (lane >= d) incl += up;
    }
    float acc = incl - run;
#pragma unroll
    for (int i = 0; i < 32; ++i) {
      acc += e[i];
      Ebf[base + i] = f2bf(e[i]);
      S[base + i] = acc;
    }
  }

  const int k8base = tile * 16 + w * 4;
#pragma unroll
  for (int r = 0; r < 4; ++r) {
    const int k8 = k8base + r;
    unsigned short v[8];
#pragma unroll
    for (int j = 0; j < 8; ++j) {
      const int ii = idx[b * LSEQ + (2047 - (k8 * 8 + j))];
      v[j] = f2bf(Wq[ii * 64 + lane]);
    }
    uint4 st;
    st.x = (unsigned int)v[0] | ((unsigned int)v[1] << 16);
    st.y = (unsigned int)v[2] | ((unsigned int)v[3] << 16);
    st.z = (unsigned int)v[4] | ((unsigned int)v[5] << 16);
    st.w = (unsigned int)v[6] | ((unsigned int)v[7] << 16);
    *(uint4*)(Agr + ((size_t)(b * 256 + k8) * 64 + lane) * 8) = st;
  }
}

__global__ __launch_bounds__(256) void k_gemm(const unsigned short* __restrict__ Agr,
                                              const unsigned short* __restrict__ Ebf,
                                              const float* __restrict__ S,
                                              float* __restrict__ P) {
  __shared__ unsigned short GL0[2208];
  __shared__ unsigned short GL1[2176];
  __shared__ float red[16][64];
  __shared__ float red2[16][64];

  const int b  = blockIdx.y;
  const int bn = 63 - (int)blockIdx.x;
  const int n0 = bn * 32;
  const int tid = threadIdx.x;
  const int w = tid >> 6;
  const int lane = tid & 63;
  const int quad = lane >> 4;
  const int lm = lane & 15;
  const int nsub = w & 1;
  const int kh = w >> 1;

  {
    const int wend = n0 + 160;
    for (int i = 96 + tid; i < wend; i += 256) {
      const int e0 = i - 127;
      const int e1 = i - 126;
      GL0[i] = (e0 >= 0 && e0 < LSEQ) ? Ebf[e0] : (unsigned short)0;
      GL1[i] = (e1 >= 0 && e1 < LSEQ) ? Ebf[e1] : (unsigned short)0;
    }
  }
  __syncthreads();

  f32x4 acc[4];
#pragma unroll
  for (int mt = 0; mt < 4; ++mt) acc[mt] = (f32x4){0.f, 0.f, 0.f, 0.f};

  const int nbase = n0 + nsub * 16;
  const int sbase = nbase + lm - 1920;
  const int kstart = 2048 - (n0 + 32);
  const int iters = bn + 1;
  const unsigned short* __restrict__ abase = Agr + (size_t)b * 256 * 64 * 8;

  union AF { uint4 u; bf16x8 v; };
  union BF { unsigned int u[4]; bf16x8 v; };
  AF a[3][4];
  BF bb[3];

#define LOAD_FRAGS(J_, SL) do {                                             \
    const int k_ = kstart + (kh + 2 * (J_)) * 32;                           \
    const int kq8_ = (k_ >> 3) + quad;                                      \
    const unsigned short* ab_ = abase + ((size_t)kq8_ * 64 + lm) * 8;       \
    a[SL][0].u = *(const uint4*)(ab_ + 0 * 128);                            \
    a[SL][1].u = *(const uint4*)(ab_ + 1 * 128);                            \
    a[SL][2].u = *(const uint4*)(ab_ + 2 * 128);                            \
    a[SL][3].u = *(const uint4*)(ab_ + 3 * 128);                            \
    const int s_ = sbase + k_ + quad * 8;                                   \
    const unsigned int* gb_ = (s_ & 1) ? (const unsigned int*)GL1           \
                                       : (const unsigned int*)GL0;          \
    const int off_ = s_ >> 1;                                               \
    bb[SL].u[0] = gb_[off_ + 0]; bb[SL].u[1] = gb_[off_ + 1];               \
    bb[SL].u[2] = gb_[off_ + 2]; bb[SL].u[3] = gb_[off_ + 3];               \
  } while (0)

#define MFMA4(SL) do {                                                      \
    acc[0] = __builtin_amdgcn_mfma_f32_16x16x32_bf16(a[SL][0].v, bb[SL].v, acc[0], 0, 0, 0); \
    acc[1] = __builtin_amdgcn_mfma_f32_16x16x32_bf16(a[SL][1].v, bb[SL].v, acc[1], 0, 0, 0); \
    acc[2] = __builtin_amdgcn_mfma_f32_16x16x32_bf16(a[SL][2].v, bb[SL].v, acc[2], 0, 0, 0); \
    acc[3] = __builtin_amdgcn_mfma_f32_16x16x32_bf16(a[SL][3].v, bb[SL].v, acc[3], 0, 0, 0); \
  } while (0)

  const int J = (iters > kh) ? ((iters - kh + 1) >> 1) : 0;
  if (J > 0) {
    LOAD_FRAGS(0, 0);
    if (J > 1) LOAD_FRAGS(1, 1);
    int j = 0;
    while (true) {
      if (j + 2 < J) LOAD_FRAGS(j + 2, 2);
      MFMA4(0);
      if (++j >= J) break;
      if (j + 2 < J) LOAD_FRAGS(j + 2, 0);
      MFMA4(1);
      if (++j >= J) break;
      if (j + 2 < J) LOAD_FRAGS(j + 2, 1);
      MFMA4(2);
      if (++j >= J) break;
    }
  }
#undef LOAD_FRAGS
#undef MFMA4

  if (kh == 1) {
    float (*rd)[64] = nsub ? red2 : red;
#pragma unroll
    for (int mt = 0; mt < 4; ++mt)
#pragma unroll
      for (int r = 0; r < 4; ++r) rd[mt * 4 + r][lane] = acc[mt][r];
  }
  __syncthreads();
  if (kh == 0) {
    float (*rd)[64] = nsub ? red2 : red;
#pragma unroll
    for (int mt = 0; mt < 4; ++mt)
#pragma unroll
      for (int r = 0; r < 4; ++r) acc[mt][r] += rd[mt * 4 + r][lane];

    const float sinv = 1.0f / S[nbase + lm];
#pragma unroll
    for (int mt = 0; mt < 4; ++mt) {
#pragma unroll
      for (int r = 0; r < 4; ++r) {
        const int c = mt * 16 + quad * 4 + r;
        P[((size_t)(b * 64 + c)) * LSEQ + nbase + lm] = __expf(acc[mt][r] * sinv);
      }
    }
  }
}

__global__ __launch_bounds__(256) void k_scanemit(const int* __restrict__ idx,
                                                  const float* __restrict__ P,
                                                  const float* __restrict__ Wv,
                                                  float* __restrict__ out) {
  __shared__ float Hs[NC][65];
  __shared__ float bins[4][64];
  const int bc = blockIdx.x;
  const int b = bc >> 6;
  const int c = bc & 63;
  const int w = threadIdx.x >> 6;
  const int lane = threadIdx.x & 63;

  const float* __restrict__ prow = P + (size_t)bc * LSEQ;
  const int* __restrict__ irow = idx + b * LSEQ;

  float p[8]; int ii[8];
#pragma unroll
  for (int r = 0; r < 8; ++r) {
    const int ch = w * 8 + r;
    p[r] = prow[ch * 64 + lane];
    ii[r] = irow[ch * 64 + lane];
  }
  for (int i = threadIdx.x; i < NC * 65; i += 256) ((float*)Hs)[i] = 0.f;
  __syncthreads();
#pragma unroll
  for (int r = 0; r < 8; ++r) atomicAdd(&Hs[w * 8 + r][ii[r]], p[r]);
  __syncthreads();

  const int half = lane >> 5, l32 = lane & 31;
#pragma unroll
  for (int r = 0; r < 8; ++r) {
    const int v = w * 16 + r * 2 + half;
    const float h = Hs[l32][v];
    float x = h;
#pragma unroll
    for (int d = 1; d < 32; d <<= 1) {
      float up = __shfl_up(x, d, 32);
      if (l32 >= d) x += up;
    }
    Hs[l32][v] = x - h;
  }
  __syncthreads();

  const float wv = Wv[0];
#pragma unroll
  for (int r = 0; r < 8; ++r) {
    const int ch = w * 8 + r;
    unsigned long long m = __ballot(ii[r] == c);
    while (m) {
      const int srel = __builtin_ctzll(m);
      m &= m - 1;
      const int t = ch * 64 + srel;
      const float pm = (lane <= srel) ? p[r] : 0.f;
      bins[w][lane] = 0.f;
      __threadfence_block();
      atomicAdd(&bins[w][ii[r]], pm);
      __threadfence_block();
      const float bin = bins[w][lane] + Hs[ch][lane];
      float z = bin;
#pragma unroll
      for (int d = 1; d < 64; d <<= 1) z += __shfl_xor(z, d);
      out[((size_t)(b * LSEQ + t)) * 64 + lane] = wv * bin / z;
    }
  }
}

extern "C" void kernel_launch(void* const* d_in, const int* in_sizes, int n_in,
                              void* d_out, int out_size, void* d_ws, size_t ws_size,
                              hipStream_t stream) {
  const int* idx     = (const int*)d_in[0];     // [16, 2048]
  const float* Wq    = (const float*)d_in[1];   // [64, 64]
  const float* Wv    = (const float*)d_in[2];   // [64, 64] (only [0,0] used)
  const float* v_emb = (const float*)d_in[3];   // [2048, 1]
  float* out = (float*)d_out;                   // [16, 2048, 64] fp32

  // workspace: S[2048] f32 | P[1024*2048] f32 | Ebf[2048] bf16 | Agr[16*256*64*8] bf16
  // sync region at +16MB: prepFlagArr[64] | cnt0[16] | flag0[16] | cnt1[16] | flag1[16]
  float* S = (float*)d_ws;
  float* P = S + LSEQ;
  unsigned short* Ebf = (unsigned short*)(P + (size_t)NB * NV * LSEQ);
  unsigned short* Agr = Ebf + LSEQ;
  unsigned int* bar = (unsigned int*)((char*)d_ws + (16u << 20));

  hipMemsetAsync(bar, 0, 16384, stream);   // zero all flag/cnt lines

  const int* a_idx = idx; const float* a_Wq = Wq; const float* a_Wv = Wv;
  const float* a_vemb = v_emb;
  unsigned short* a_Agr = Agr; unsigned short* a_Ebf = Ebf;
  float* a_S = S; float* a_P = P; float* a_out = out;
  unsigned int* a_bar = bar;
  void* args[] = {(void*)&a_idx, (void*)&a_Wq, (void*)&a_Wv, (void*)&a_vemb,
                  (void*)&a_Agr, (void*)&a_Ebf, (void*)&a_S, (void*)&a_P,
                  (void*)&a_out, (void*)&a_bar};

  hipError_t cerr = hipLaunchCooperativeKernel((void*)k_fused, dim3(NBLK),
                                               dim3(256), args, 0, stream);
  if (cerr != hipSuccess) {
    (void)hipGetLastError();   // clear sticky error, fall back to 3-kernel path
    k_gather<<<NB * 16, 256, 0, stream>>>(idx, Wq, v_emb, Agr, Ebf, S);
    k_gemm<<<dim3(64, NB), 256, 0, stream>>>(Agr, Ebf, S, P);
    k_scanemit<<<NB * NV, 256, 0, stream>>>(idx, P, Wv, out);
  }
}

// Round 7
// 149.862 us; speedup vs baseline: 1.4693x; 1.4693x over previous
//
#include <hip/hip_runtime.h>

// B=16, L=2048, V=64.
// Algebraic reduction (e is one-hot):
//   E[d] = exp(v_emb[d]); S[t] = prefix_sum(E)[t]
//   F[b,c,s] = sum_{k<=s} E[s-k] * Wq[idx[b,k], c]            (causal Toeplitz GEMM)
//   P[b,c,s] = exp(F[b,c,s] / S[s])                           (softmax w/o max; scores tiny)
//   out[b,t,v] = Wv00 * (sum_{s<=t, idx[b,s]==v} P[b,c_t,s]) / (sum_{s<=t} P[b,c_t,s]),  c_t = idx[b,t]
//
// R22: occupancy theory falsified (R21: Occ 20->40% but 100->135us). What
// correlates with duration across ALL 5 fused variants is the count of
// agent-scope cache-maintenance ops (release=L2 writeback, acquire=L2 inv on
// non-coherent per-XCD L2s): ~2k ops->92.5us, ~2.5k->100, ~5k->135,
// acquire-polling->180-191. This round: ZERO fences. Cross-block data goes
// through the coherent path instead: Agr/P accessed via relaxed-agent
// atomics (sc1: bypass XCD L2, served by shared Infinity Cache; both are
// single-use streaming arrays so losing L2 costs nothing). Ebf/S global
// round-trip deleted: every block computes E/S itself (2048 expf + block
// scan ~2us) straight into its GL0/GL1 LDS windows. Barriers = syncthreads
// (HW drains vmcnt) + relaxed fetch_add + relaxed flag + relaxed poll.
// Predicted k_fused 135 -> 25-45us; >=80us falsifies -> revert to 3-kernel.

#define LSEQ 2048
#define NB 16
#define NV 64
#define NC 32             // 32 chunks of 64
#define NBLK 1024         // fused grid size
#define BPB 64            // blocks per batch

typedef __attribute__((ext_vector_type(8))) short bf16x8;
typedef __attribute__((ext_vector_type(4))) float f32x4;

__device__ __forceinline__ unsigned short f2bf(float f) {   // RNE float->bf16
  unsigned int u = __float_as_uint(f);
  return (unsigned short)((u + 0x7FFFu + ((u >> 16) & 1u)) >> 16);
}

// ---- per-batch barrier, FENCE-FREE -------------------------------------
// Soundness: __syncthreads() on gfx950 drains each wave's vmcnt before
// s_barrier, so every thread's sc1 (coherence-point) stores are acked at the
// Infinity Cache before tid0 issues the relaxed RMW; the flag store and the
// consumers' relaxed sc1 loads hit the same coherence point. No L2
// writeback/invalidate is ever needed because no cross-block data lives in
// an XCD L2.
__device__ __forceinline__ void bb_arrive(unsigned int* cnt, unsigned int* flag) {
  __syncthreads();
  if (threadIdx.x == 0) {
    unsigned int old = __hip_atomic_fetch_add(cnt, 1u, __ATOMIC_RELAXED,
                                              __HIP_MEMORY_SCOPE_AGENT);
    if (old == BPB - 1u)
      __hip_atomic_store(flag, 1u, __ATOMIC_RELAXED, __HIP_MEMORY_SCOPE_AGENT);
  }
}
__device__ __forceinline__ void bb_wait(unsigned int* flag) {
  if (threadIdx.x == 0) {
    while (__hip_atomic_load(flag, __ATOMIC_RELAXED,
                             __HIP_MEMORY_SCOPE_AGENT) == 0u)
      __builtin_amdgcn_s_sleep(2);
  }
  __syncthreads();
}

// =====================================================================
// Fused kernel, grid=1024: phase0 gather | batchbar | phase1 E/S-compute
// + GEMM (1 tile/block) | batchbar | phase2 scan+emit (1 (b,c)/block).
// =====================================================================
__global__ __launch_bounds__(256, 4) void k_fused(
    const int* __restrict__ idx, const float* __restrict__ Wq,
    const float* __restrict__ Wv, const float* __restrict__ v_emb,
    unsigned short* __restrict__ Agr, float* __restrict__ P,
    float* __restrict__ out, unsigned int* __restrict__ bar) {
  union SMem {
    struct {  // phase 1 (GEMM)
      unsigned short GL0[2208];   // GL0[i] = (127<=i<2175) ? E[i-127] : 0
      unsigned short GL1[2176];   // GL1[i] = GLv(i+1)
      float Sarr[2048];           // S prefix sums (this block computes)
      float red[16][64];
      float red2[16][64];
    } g;
    struct {  // phase 2 (scan+emit)
      float Hs[NC][65];
      float pl[4][64];
      unsigned long long mk[4][64];
    } s;
  };
  __shared__ SMem sm;
  __shared__ float swsum[4];

  const int bid = blockIdx.x;     // [0, 1024)
  const int tid = threadIdx.x;
  const int w = tid >> 6;
  const int lane = tid & 63;
  const int b = bid >> 6;         // this block's batch, ALL phases

  // sync layout in bar (uints; 32 uints = one 128B line each):
  // cnt0[b] @b*32 | flag0[b] @512+b*32 | cnt1[b] @1024+b*32 | flag1[b] @1536+b*32
  unsigned int* cnt0b  = bar +    0 + b * 32;
  unsigned int* flag0b = bar +  512 + b * 32;
  unsigned int* cnt1b  = bar + 1024 + b * 32;
  unsigned int* flag1b = bar + 1536 + b * 32;

  // ---------------- phase 0: gather (Agr via coherent sc1 stores) -----
  {
    const int sub = bid & 63;
    const int k8 = sub * 4 + w;   // 1 k8-group per wave
    unsigned short v[8];
#pragma unroll
    for (int j = 0; j < 8; ++j) {
      const int ii = idx[b * LSEQ + (2047 - (k8 * 8 + j))];  // wave-uniform
      v[j] = f2bf(Wq[ii * 64 + lane]);                       // coalesced row read
    }
    const unsigned long long lo =
        (unsigned long long)((unsigned int)v[0] | ((unsigned int)v[1] << 16)) |
        ((unsigned long long)((unsigned int)v[2] | ((unsigned int)v[3] << 16)) << 32);
    const unsigned long long hi =
        (unsigned long long)((unsigned int)v[4] | ((unsigned int)v[5] << 16)) |
        ((unsigned long long)((unsigned int)v[6] | ((unsigned int)v[7] << 16)) << 32);
    unsigned long long* dst =
        (unsigned long long*)(Agr + ((size_t)(b * 256 + k8) * 64 + lane) * 8);
    __hip_atomic_store(dst + 0, lo, __ATOMIC_RELAXED, __HIP_MEMORY_SCOPE_AGENT);
    __hip_atomic_store(dst + 1, hi, __ATOMIC_RELAXED, __HIP_MEMORY_SCOPE_AGENT);
  }
  bb_arrive(cnt0b, flag0b);        // phase-0 done for this block

  // ---------------- phase 1: E/S in-block + MFMA GEMM, 1 tile/block ---
  const int bn = 63 - (bid & 63);          // heavy (long-K) blocks first
  const int n0 = bn * 32;
  const int quad = lane >> 4;
  const int lm = lane & 15;
  const int nsub = w & 1;                  // n-offset 0 / 16
  const int kh = w >> 1;                   // k-half 0 / 1
  const int nbase = n0 + nsub * 16;

  {  // E/S compute: each block independently (no cross-block dep at all)
    float ev[8], ps8[8];
    float tot = 0.f;
    const int t0 = tid * 8;
#pragma unroll
    for (int j = 0; j < 8; ++j) {
      const float e = expf(v_emb[t0 + j]);
      tot += e; ev[j] = e; ps8[j] = tot;
    }
    float ws = tot;                        // wave-inclusive scan of thread sums
#pragma unroll
    for (int d = 1; d < 64; d <<= 1) {
      float up = __shfl_up(ws, d);
      if (lane >= d) ws += up;
    }
    if (lane == 63) swsum[w] = ws;
    __syncthreads();
    float wbase = 0.f;
#pragma unroll
    for (int k = 0; k < 4; ++k) if (k < w) wbase += swsum[k];
    const float base = wbase + (ws - tot); // exclusive base for this thread
#pragma unroll
    for (int j = 0; j < 8; ++j) {
      const int d = t0 + j;
      sm.g.Sarr[d] = base + ps8[j];
      const unsigned short bv = f2bf(ev[j]);
      sm.g.GL0[d + 127] = bv;              // GL0[i]=E[i-127]
      sm.g.GL1[d + 126] = bv;              // GL1[i]=E[i-126]
    }
    if (tid < 31) sm.g.GL0[96 + tid] = 0;  // zero [96,127)
    if (tid < 30) sm.g.GL1[96 + tid] = 0;  // zero [96,126)
    if (tid == 0) { sm.g.GL0[2175] = 0; sm.g.GL1[2174] = 0; sm.g.GL1[2175] = 0; }
    __syncthreads();
  }
  const float sinv = 1.0f / sm.g.Sarr[nbase + lm];  // keep in reg past red reuse

  bb_wait(flag0b);   // Agr[b] complete (coherent stores acked at IC)

  {
    const unsigned long long* __restrict__ abase64 =
        (const unsigned long long*)(Agr + (size_t)b * 256 * 64 * 8);
    const int sbase = nbase + lm - 1920;
    const int kstart = 2048 - (n0 + 32);   // multiple of 32
    const int iters = bn + 1;              // total 32-k steps for this tile

    f32x4 acc[4];
#pragma unroll
    for (int mt = 0; mt < 4; ++mt) acc[mt] = (f32x4){0.f, 0.f, 0.f, 0.f};

    union AF { unsigned long long q[2]; bf16x8 v; };
    union BF { unsigned int u[4]; bf16x8 v; };
    AF a[3][4];
    BF bb[3];

#define LOAD_FRAGS(J_, SL) do {                                             \
    const int k_ = kstart + (kh + 2 * (J_)) * 32;                           \
    const int kq8_ = (k_ >> 3) + quad;                                      \
    const unsigned long long* ab_ = abase64 + (size_t)(kq8_ * 64 + lm) * 2; \
    a[SL][0].q[0] = __hip_atomic_load(ab_ +  0, __ATOMIC_RELAXED, __HIP_MEMORY_SCOPE_AGENT); \
    a[SL][0].q[1] = __hip_atomic_load(ab_ +  1, __ATOMIC_RELAXED, __HIP_MEMORY_SCOPE_AGENT); \
    a[SL][1].q[0] = __hip_atomic_load(ab_ + 32, __ATOMIC_RELAXED, __HIP_MEMORY_SCOPE_AGENT); \
    a[SL][1].q[1] = __hip_atomic_load(ab_ + 33, __ATOMIC_RELAXED, __HIP_MEMORY_SCOPE_AGENT); \
    a[SL][2].q[0] = __hip_atomic_load(ab_ + 64, __ATOMIC_RELAXED, __HIP_MEMORY_SCOPE_AGENT); \
    a[SL][2].q[1] = __hip_atomic_load(ab_ + 65, __ATOMIC_RELAXED, __HIP_MEMORY_SCOPE_AGENT); \
    a[SL][3].q[0] = __hip_atomic_load(ab_ + 96, __ATOMIC_RELAXED, __HIP_MEMORY_SCOPE_AGENT); \
    a[SL][3].q[1] = __hip_atomic_load(ab_ + 97, __ATOMIC_RELAXED, __HIP_MEMORY_SCOPE_AGENT); \
    const int s_ = sbase + k_ + quad * 8;                                   \
    const unsigned int* gb_ = (s_ & 1) ? (const unsigned int*)sm.g.GL1      \
                                       : (const unsigned int*)sm.g.GL0;     \
    const int off_ = s_ >> 1;                                               \
    bb[SL].u[0] = gb_[off_ + 0]; bb[SL].u[1] = gb_[off_ + 1];               \
    bb[SL].u[2] = gb_[off_ + 2]; bb[SL].u[3] = gb_[off_ + 3];               \
  } while (0)

#define MFMA4(SL) do {                                                      \
    acc[0] = __builtin_amdgcn_mfma_f32_16x16x32_bf16(a[SL][0].v, bb[SL].v, acc[0], 0, 0, 0); \
    acc[1] = __builtin_amdgcn_mfma_f32_16x16x32_bf16(a[SL][1].v, bb[SL].v, acc[1], 0, 0, 0); \
    acc[2] = __builtin_amdgcn_mfma_f32_16x16x32_bf16(a[SL][2].v, bb[SL].v, acc[2], 0, 0, 0); \
    acc[3] = __builtin_amdgcn_mfma_f32_16x16x32_bf16(a[SL][3].v, bb[SL].v, acc[3], 0, 0, 0); \
  } while (0)

    const int J = (iters > kh) ? ((iters - kh + 1) >> 1) : 0;  // wave-iters
    if (J > 0) {
      LOAD_FRAGS(0, 0);
      if (J > 1) LOAD_FRAGS(1, 1);
      int j = 0;
      while (true) {
        if (j + 2 < J) LOAD_FRAGS(j + 2, 2);
        MFMA4(0);
        if (++j >= J) break;
        if (j + 2 < J) LOAD_FRAGS(j + 2, 0);
        MFMA4(1);
        if (++j >= J) break;
        if (j + 2 < J) LOAD_FRAGS(j + 2, 1);
        MFMA4(2);
        if (++j >= J) break;
      }
    }
#undef LOAD_FRAGS
#undef MFMA4

    // reduce k-half 1 into k-half 0 via LDS (lane-contiguous, conflict-free)
    if (kh == 1) {
      float (*rd)[64] = nsub ? sm.g.red2 : sm.g.red;
#pragma unroll
      for (int mt = 0; mt < 4; ++mt)
#pragma unroll
        for (int r = 0; r < 4; ++r) rd[mt * 4 + r][lane] = acc[mt][r];
    }
    __syncthreads();
    if (kh == 0) {
      float (*rd)[64] = nsub ? sm.g.red2 : sm.g.red;
#pragma unroll
      for (int mt = 0; mt < 4; ++mt)
#pragma unroll
        for (int r = 0; r < 4; ++r) acc[mt][r] += rd[mt * 4 + r][lane];

      // epilogue: C/D layout col(s)=lm, row(c)=quad*4+r; coherent P stores
#pragma unroll
      for (int mt = 0; mt < 4; ++mt) {
#pragma unroll
        for (int r = 0; r < 4; ++r) {
          const int c = mt * 16 + quad * 4 + r;
          const float val = __expf(acc[mt][r] * sinv);
          __hip_atomic_store(&P[((size_t)(b * 64 + c)) * LSEQ + nbase + lm],
                             val, __ATOMIC_RELAXED, __HIP_MEMORY_SCOPE_AGENT);
        }
      }
    }
  }
  bb_arrive(cnt1b, flag1b);        // P[b] columns from this block complete

  // ---------------- phase 2: chunk-hists + scan + fence-free emission --
  {
    const int c = bid & 63;        // this block's vocab bin; bc = bid
    const int* __restrict__ irow = idx + b * LSEQ;
    int ii[8];
#pragma unroll
    for (int r = 0; r < 8; ++r)    // idx-only loads: overlap the wait
      ii[r] = irow[(w * 8 + r) * 64 + lane];

    bb_wait(flag1b);               // all of batch b's P rows ready

    const float* __restrict__ prow = P + (size_t)bid * LSEQ;
    float p[8];
#pragma unroll
    for (int r = 0; r < 8; ++r)    // coherent sc1 loads (single-use stream)
      p[r] = __hip_atomic_load(prow + (w * 8 + r) * 64 + lane,
                               __ATOMIC_RELAXED, __HIP_MEMORY_SCOPE_AGENT);

    for (int i = tid; i < NC * 65; i += 256) ((float*)sm.s.Hs)[i] = 0.f;
    __syncthreads();
#pragma unroll
    for (int r = 0; r < 8; ++r) atomicAdd(&sm.s.Hs[w * 8 + r][ii[r]], p[r]);
    __syncthreads();

    // exclusive scan across chunks, per bin: 2 bins per pass (lane halves)
    const int hhalf = lane >> 5, l32 = lane & 31;
#pragma unroll
    for (int r = 0; r < 8; ++r) {
      const int v = w * 16 + r * 2 + hhalf;
      const float h = sm.s.Hs[l32][v];
      float x = h;
#pragma unroll
      for (int d = 1; d < 32; d <<= 1) {
        float up = __shfl_up(x, d, 32);
        if (l32 >= d) x += up;
      }
      sm.s.Hs[l32][v] = x - h;     // exclusive
    }
    __syncthreads();

    const float wv = Wv[0];
#pragma unroll
    for (int r = 0; r < 8; ++r) {
      const int ch = w * 8 + r;
      unsigned long long em = __ballot(ii[r] == c);   // emission points
      if (em == 0ull) continue;                       // wave-uniform skip
      // per-chunk setup (wave-synchronous LDS, no fences):
      sm.s.pl[w][lane] = p[r];                        // stage p
      sm.s.mk[w][lane] = 0ull;
      atomicOr(&sm.s.mk[w][ii[r]], 1ull << lane);     // bin <- source lanes
      float ps = p[r];                                // within-chunk prefix
#pragma unroll
      for (int d = 1; d < 64; d <<= 1) {
        float up = __shfl_up(ps, d);
        if (lane >= d) ps += up;
      }
      const float hbase = sm.s.Hs[ch][lane];
      float zex = hbase;                              // Z_excl = sum_v Hs
#pragma unroll
      for (int d = 1; d < 64; d <<= 1) zex += __shfl_xor(zex, d);
      const unsigned long long myMask = sm.s.mk[w][lane];
      while (em) {
        const int srel = __builtin_ctzll(em);
        em &= em - 1;
        unsigned long long mm = myMask &
            ((srel == 63) ? ~0ull : ((1ull << (srel + 1)) - 1ull));
        float B = hbase;                              // bin value at this t
        while (mm) { const int l = __builtin_ctzll(mm); mm &= mm - 1; B += sm.s.pl[w][l]; }
        const float z = zex + __shfl(ps, srel);       // denominator
        out[((size_t)(b * LSEQ + ch * 64 + srel)) * 64 + lane] = wv * B / z;
      }
    }
  }
}

// =====================================================================
// Fallback path: the verified 3-kernel pipeline (R11), used only if the
// cooperative launch is rejected.
// =====================================================================
__global__ __launch_bounds__(256) void k_gather(const int* __restrict__ idx,
                                                const float* __restrict__ Wq,
                                                const float* __restrict__ v_emb,
                                                unsigned short* __restrict__ Agr,
                                                unsigned short* __restrict__ Ebf,
                                                float* __restrict__ S) {
  const int b = blockIdx.x >> 4;
  const int tile = blockIdx.x & 15;
  const int w = threadIdx.x >> 6;
  const int lane = threadIdx.x & 63;

  if (blockIdx.x == 0 && threadIdx.x < 64) {
    const int base = lane * 32;
    float e[32];
    float run = 0.f;
#pragma unroll
    for (int i = 0; i < 32; ++i) { e[i] = expf(v_emb[base + i]); run += e[i]; }
    float incl = run;
#pragma unroll
    for (int d = 1; d < 64; d <<= 1) {
      float up = __shfl_up(incl, d);
      if (lane >= d) incl += up;
    }
    float acc = incl - run;
#pragma unroll
    for (int i = 0; i < 32; ++i) {
      acc += e[i];
      Ebf[base + i] = f2bf(e[i]);
      S[base + i] = acc;
    }
  }

  const int k8base = tile * 16 + w * 4;
#pragma unroll
  for (int r = 0; r < 4; ++r) {
    const int k8 = k8base + r;
    unsigned short v[8];
#pragma unroll
    for (int j = 0; j < 8; ++j) {
      const int ii = idx[b * LSEQ + (2047 - (k8 * 8 + j))];
      v[j] = f2bf(Wq[ii * 64 + lane]);
    }
    uint4 st;
    st.x = (unsigned int)v[0] | ((unsigned int)v[1] << 16);
    st.y = (unsigned int)v[2] | ((unsigned int)v[3] << 16);
    st.z = (unsigned int)v[4] | ((unsigned int)v[5] << 16);
    st.w = (unsigned int)v[6] | ((unsigned int)v[7] << 16);
    *(uint4*)(Agr + ((size_t)(b * 256 + k8) * 64 + lane) * 8) = st;
  }
}

__global__ __launch_bounds__(256) void k_gemm(const unsigned short* __restrict__ Agr,
                                              const unsigned short* __restrict__ Ebf,
                                              const float* __restrict__ S,
                                              float* __restrict__ P) {
  __shared__ unsigned short GL0[2208];
  __shared__ unsigned short GL1[2176];
  __shared__ float red[16][64];
  __shared__ float red2[16][64];

  const int b  = blockIdx.y;
  const int bn = 63 - (int)blockIdx.x;
  const int n0 = bn * 32;
  const int tid = threadIdx.x;
  const int w = tid >> 6;
  const int lane = tid & 63;
  const int quad = lane >> 4;
  const int lm = lane & 15;
  const int nsub = w & 1;
  const int kh = w >> 1;

  {
    const int wend = n0 + 160;
    for (int i = 96 + tid; i < wend; i += 256) {
      const int e0 = i - 127;
      const int e1 = i - 126;
      GL0[i] = (e0 >= 0 && e0 < LSEQ) ? Ebf[e0] : (unsigned short)0;
      GL1[i] = (e1 >= 0 && e1 < LSEQ) ? Ebf[e1] : (unsigned short)0;
    }
  }
  __syncthreads();

  f32x4 acc[4];
#pragma unroll
  for (int mt = 0; mt < 4; ++mt) acc[mt] = (f32x4){0.f, 0.f, 0.f, 0.f};

  const int nbase = n0 + nsub * 16;
  const int sbase = nbase + lm - 1920;
  const int kstart = 2048 - (n0 + 32);
  const int iters = bn + 1;
  const unsigned short* __restrict__ abase = Agr + (size_t)b * 256 * 64 * 8;

  union AF { uint4 u; bf16x8 v; };
  union BF { unsigned int u[4]; bf16x8 v; };
  AF a[3][4];
  BF bb[3];

#define LOAD_FRAGS(J_, SL) do {                                             \
    const int k_ = kstart + (kh + 2 * (J_)) * 32;                           \
    const int kq8_ = (k_ >> 3) + quad;                                      \
    const unsigned short* ab_ = abase + ((size_t)kq8_ * 64 + lm) * 8;       \
    a[SL][0].u = *(const uint4*)(ab_ + 0 * 128);                            \
    a[SL][1].u = *(const uint4*)(ab_ + 1 * 128);                            \
    a[SL][2].u = *(const uint4*)(ab_ + 2 * 128);                            \
    a[SL][3].u = *(const uint4*)(ab_ + 3 * 128);                            \
    const int s_ = sbase + k_ + quad * 8;                                   \
    const unsigned int* gb_ = (s_ & 1) ? (const unsigned int*)GL1           \
                                       : (const unsigned int*)GL0;          \
    const int off_ = s_ >> 1;                                               \
    bb[SL].u[0] = gb_[off_ + 0]; bb[SL].u[1] = gb_[off_ + 1];               \
    bb[SL].u[2] = gb_[off_ + 2]; bb[SL].u[3] = gb_[off_ + 3];               \
  } while (0)

#define MFMA4(SL) do {                                                      \
    acc[0] = __builtin_amdgcn_mfma_f32_16x16x32_bf16(a[SL][0].v, bb[SL].v, acc[0], 0, 0, 0); \
    acc[1] = __builtin_amdgcn_mfma_f32_16x16x32_bf16(a[SL][1].v, bb[SL].v, acc[1], 0, 0, 0); \
    acc[2] = __builtin_amdgcn_mfma_f32_16x16x32_bf16(a[SL][2].v, bb[SL].v, acc[2], 0, 0, 0); \
    acc[3] = __builtin_amdgcn_mfma_f32_16x16x32_bf16(a[SL][3].v, bb[SL].v, acc[3], 0, 0, 0); \
  } while (0)

  const int J = (iters > kh) ? ((iters - kh + 1) >> 1) : 0;
  if (J > 0) {
    LOAD_FRAGS(0, 0);
    if (J > 1) LOAD_FRAGS(1, 1);
    int j = 0;
    while (true) {
      if (j + 2 < J) LOAD_FRAGS(j + 2, 2);
      MFMA4(0);
      if (++j >= J) break;
      if (j + 2 < J) LOAD_FRAGS(j + 2, 0);
      MFMA4(1);
      if (++j >= J) break;
      if (j + 2 < J) LOAD_FRAGS(j + 2, 1);
      MFMA4(2);
      if (++j >= J) break;
    }
  }
#undef LOAD_FRAGS
#undef MFMA4

  if (kh == 1) {
    float (*rd)[64] = nsub ? red2 : red;
#pragma unroll
    for (int mt = 0; mt < 4; ++mt)
#pragma unroll
      for (int r = 0; r < 4; ++r) rd[mt * 4 + r][lane] = acc[mt][r];
  }
  __syncthreads();
  if (kh == 0) {
    float (*rd)[64] = nsub ? red2 : red;
#pragma unroll
    for (int mt = 0; mt < 4; ++mt)
#pragma unroll
      for (int r = 0; r < 4; ++r) acc[mt][r] += rd[mt * 4 + r][lane];

    const float sinv = 1.0f / S[nbase + lm];
#pragma unroll
    for (int mt = 0; mt < 4; ++mt) {
#pragma unroll
      for (int r = 0; r < 4; ++r) {
        const int c = mt * 16 + quad * 4 + r;
        P[((size_t)(b * 64 + c)) * LSEQ + nbase + lm] = __expf(acc[mt][r] * sinv);
      }
    }
  }
}

__global__ __launch_bounds__(256) void k_scanemit(const int* __restrict__ idx,
                                                  const float* __restrict__ P,
                                                  const float* __restrict__ Wv,
                                                  float* __restrict__ out) {
  __shared__ float Hs[NC][65];
  __shared__ float bins[4][64];
  const int bc = blockIdx.x;
  const int b = bc >> 6;
  const int c = bc & 63;
  const int w = threadIdx.x >> 6;
  const int lane = threadIdx.x & 63;

  const float* __restrict__ prow = P + (size_t)bc * LSEQ;
  const int* __restrict__ irow = idx + b * LSEQ;

  float p[8]; int ii[8];
#pragma unroll
  for (int r = 0; r < 8; ++r) {
    const int ch = w * 8 + r;
    p[r] = prow[ch * 64 + lane];
    ii[r] = irow[ch * 64 + lane];
  }
  for (int i = threadIdx.x; i < NC * 65; i += 256) ((float*)Hs)[i] = 0.f;
  __syncthreads();
#pragma unroll
  for (int r = 0; r < 8; ++r) atomicAdd(&Hs[w * 8 + r][ii[r]], p[r]);
  __syncthreads();

  const int half = lane >> 5, l32 = lane & 31;
#pragma unroll
  for (int r = 0; r < 8; ++r) {
    const int v = w * 16 + r * 2 + half;
    const float h = Hs[l32][v];
    float x = h;
#pragma unroll
    for (int d = 1; d < 32; d <<= 1) {
      float up = __shfl_up(x, d, 32);
      if (l32 >= d) x += up;
    }
    Hs[l32][v] = x - h;
  }
  __syncthreads();

  const float wv = Wv[0];
#pragma unroll
  for (int r = 0; r < 8; ++r) {
    const int ch = w * 8 + r;
    unsigned long long m = __ballot(ii[r] == c);
    while (m) {
      const int srel = __builtin_ctzll(m);
      m &= m - 1;
      const int t = ch * 64 + srel;
      const float pm = (lane <= srel) ? p[r] : 0.f;
      bins[w][lane] = 0.f;
      __threadfence_block();
      atomicAdd(&bins[w][ii[r]], pm);
      __threadfence_block();
      const float bin = bins[w][lane] + Hs[ch][lane];
      float z = bin;
#pragma unroll
      for (int d = 1; d < 64; d <<= 1) z += __shfl_xor(z, d);
      out[((size_t)(b * LSEQ + t)) * 64 + lane] = wv * bin / z;
    }
  }
}

extern "C" void kernel_launch(void* const* d_in, const int* in_sizes, int n_in,
                              void* d_out, int out_size, void* d_ws, size_t ws_size,
                              hipStream_t stream) {
  const int* idx     = (const int*)d_in[0];     // [16, 2048]
  const float* Wq    = (const float*)d_in[1];   // [64, 64]
  const float* Wv    = (const float*)d_in[2];   // [64, 64] (only [0,0] used)
  const float* v_emb = (const float*)d_in[3];   // [2048, 1]
  float* out = (float*)d_out;                   // [16, 2048, 64] fp32

  // workspace: S[2048] f32 | P[1024*2048] f32 | Ebf[2048] bf16 | Agr[16*256*64*8] bf16
  // sync region at +16MB: cnt0[16] | flag0[16] | cnt1[16] | flag1[16] (128B lines)
  float* S = (float*)d_ws;
  float* P = S + LSEQ;
  unsigned short* Ebf = (unsigned short*)(P + (size_t)NB * NV * LSEQ);
  unsigned short* Agr = Ebf + LSEQ;
  unsigned int* bar = (unsigned int*)((char*)d_ws + (16u << 20));

  hipMemsetAsync(bar, 0, 8192, stream);   // zero all cnt/flag lines

  const int* a_idx = idx; const float* a_Wq = Wq; const float* a_Wv = Wv;
  const float* a_vemb = v_emb;
  unsigned short* a_Agr = Agr;
  float* a_P = P; float* a_out = out;
  unsigned int* a_bar = bar;
  void* args[] = {(void*)&a_idx, (void*)&a_Wq, (void*)&a_Wv, (void*)&a_vemb,
                  (void*)&a_Agr, (void*)&a_P, (void*)&a_out, (void*)&a_bar};

  hipError_t cerr = hipLaunchCooperativeKernel((void*)k_fused, dim3(NBLK),
                                               dim3(256), args, 0, stream);
  if (cerr != hipSuccess) {
    (void)hipGetLastError();   // clear sticky error, fall back to 3-kernel path
    k_gather<<<NB * 16, 256, 0, stream>>>(idx, Wq, v_emb, Agr, Ebf, S);
    k_gemm<<<dim3(64, NB), 256, 0, stream>>>(Agr, Ebf, S, P);
    k_scanemit<<<NB * NV, 256, 0, stream>>>(idx, P, Wv, out);
  }
}

// Round 8
// 123.027 us; speedup vs baseline: 1.7898x; 1.2181x over previous
//
#include <hip/hip_runtime.h>

// B=16, L=2048, V=64.
// Algebraic reduction (e is one-hot):
//   E[d] = exp(v_emb[d]); S[t] = prefix_sum(E)[t]
//   F[b,c,s] = sum_{k<=s} E[s-k] * Wq[idx[b,k], c]            (causal Toeplitz GEMM)
//   P[b,c,s] = exp(F[b,c,s] / S[s])                           (softmax w/o max; scores tiny)
//   out[b,t,v] = Wv00 * (sum_{s<=t, idx[b,s]==v} P[b,c_t,s]) / (sum_{s<=t} P[b,c_t,s]),  c_t = idx[b,t]
//
// R23: R22 (zero-fence, coherent sc1 path) cut k_fused 135->62us, confirming
// the cache-maintenance theory. Remaining: (1) ~40us launch overhead SPECIFIC
// to hipLaunchCooperativeKernel under graph capture (total-poison-kernel =
// 38-43us across R19-R22 vs ~5-8us for plain launches in the 3-kernel
// baseline); (2) k_fused's internal waits. This round changes ONE thing:
// plain <<<>>> launch of the byte-identical kernel. Safety: co-residency by
// capacity arithmetic — VGPR 64 (8 waves/SIMD), LDS 25.6KB (6 blocks/CU) =>
// capacity 1536 blocks > grid 1024 = 4/CU exactly; spin barriers cannot
// deadlock. Predicted: k_fused ~62 unchanged, total 149.9 -> 112-118.

#define LSEQ 2048
#define NB 16
#define NV 64
#define NC 32             // 32 chunks of 64
#define NBLK 1024         // fused grid size
#define BPB 64            // blocks per batch

typedef __attribute__((ext_vector_type(8))) short bf16x8;
typedef __attribute__((ext_vector_type(4))) float f32x4;

__device__ __forceinline__ unsigned short f2bf(float f) {   // RNE float->bf16
  unsigned int u = __float_as_uint(f);
  return (unsigned short)((u + 0x7FFFu + ((u >> 16) & 1u)) >> 16);
}

// ---- per-batch barrier, FENCE-FREE -------------------------------------
// Soundness: __syncthreads() drains each wave's vmcnt before s_barrier, so
// every thread's sc1 (coherence-point) stores are acked at the Infinity
// Cache before tid0 issues the relaxed RMW; the flag store and consumers'
// relaxed sc1 loads hit the same coherence point. No L2 writeback/inv needed
// because no cross-block data ever lives in an XCD L2.
__device__ __forceinline__ void bb_arrive(unsigned int* cnt, unsigned int* flag) {
  __syncthreads();
  if (threadIdx.x == 0) {
    unsigned int old = __hip_atomic_fetch_add(cnt, 1u, __ATOMIC_RELAXED,
                                              __HIP_MEMORY_SCOPE_AGENT);
    if (old == BPB - 1u)
      __hip_atomic_store(flag, 1u, __ATOMIC_RELAXED, __HIP_MEMORY_SCOPE_AGENT);
  }
}
__device__ __forceinline__ void bb_wait(unsigned int* flag) {
  if (threadIdx.x == 0) {
    while (__hip_atomic_load(flag, __ATOMIC_RELAXED,
                             __HIP_MEMORY_SCOPE_AGENT) == 0u)
      __builtin_amdgcn_s_sleep(2);
  }
  __syncthreads();
}

// =====================================================================
// Fused kernel, grid=1024 (plain launch, all blocks resident by capacity):
// phase0 gather | batchbar | phase1 E/S-compute + GEMM (1 tile/block) |
// batchbar | phase2 scan+emit (1 (b,c)/block). Identical to R22 (verified).
// =====================================================================
__global__ __launch_bounds__(256, 4) void k_fused(
    const int* __restrict__ idx, const float* __restrict__ Wq,
    const float* __restrict__ Wv, const float* __restrict__ v_emb,
    unsigned short* __restrict__ Agr, float* __restrict__ P,
    float* __restrict__ out, unsigned int* __restrict__ bar) {
  union SMem {
    struct {  // phase 1 (GEMM)
      unsigned short GL0[2208];   // GL0[i] = (127<=i<2175) ? E[i-127] : 0
      unsigned short GL1[2176];   // GL1[i] = GLv(i+1)
      float Sarr[2048];           // S prefix sums (this block computes)
      float red[16][64];
      float red2[16][64];
    } g;
    struct {  // phase 2 (scan+emit)
      float Hs[NC][65];
      float pl[4][64];
      unsigned long long mk[4][64];
    } s;
  };
  __shared__ SMem sm;
  __shared__ float swsum[4];

  const int bid = blockIdx.x;     // [0, 1024)
  const int tid = threadIdx.x;
  const int w = tid >> 6;
  const int lane = tid & 63;
  const int b = bid >> 6;         // this block's batch, ALL phases

  // sync layout in bar (uints; 32 uints = one 128B line each):
  // cnt0[b] @b*32 | flag0[b] @512+b*32 | cnt1[b] @1024+b*32 | flag1[b] @1536+b*32
  unsigned int* cnt0b  = bar +    0 + b * 32;
  unsigned int* flag0b = bar +  512 + b * 32;
  unsigned int* cnt1b  = bar + 1024 + b * 32;
  unsigned int* flag1b = bar + 1536 + b * 32;

  // ---------------- phase 0: gather (Agr via coherent sc1 stores) -----
  {
    const int sub = bid & 63;
    const int k8 = sub * 4 + w;   // 1 k8-group per wave
    unsigned short v[8];
#pragma unroll
    for (int j = 0; j < 8; ++j) {
      const int ii = idx[b * LSEQ + (2047 - (k8 * 8 + j))];  // wave-uniform
      v[j] = f2bf(Wq[ii * 64 + lane]);                       // coalesced row read
    }
    const unsigned long long lo =
        (unsigned long long)((unsigned int)v[0] | ((unsigned int)v[1] << 16)) |
        ((unsigned long long)((unsigned int)v[2] | ((unsigned int)v[3] << 16)) << 32);
    const unsigned long long hi =
        (unsigned long long)((unsigned int)v[4] | ((unsigned int)v[5] << 16)) |
        ((unsigned long long)((unsigned int)v[6] | ((unsigned int)v[7] << 16)) << 32);
    unsigned long long* dst =
        (unsigned long long*)(Agr + ((size_t)(b * 256 + k8) * 64 + lane) * 8);
    __hip_atomic_store(dst + 0, lo, __ATOMIC_RELAXED, __HIP_MEMORY_SCOPE_AGENT);
    __hip_atomic_store(dst + 1, hi, __ATOMIC_RELAXED, __HIP_MEMORY_SCOPE_AGENT);
  }
  bb_arrive(cnt0b, flag0b);        // phase-0 done for this block

  // ---------------- phase 1: E/S in-block + MFMA GEMM, 1 tile/block ---
  const int bn = 63 - (bid & 63);          // heavy (long-K) blocks first
  const int n0 = bn * 32;
  const int quad = lane >> 4;
  const int lm = lane & 15;
  const int nsub = w & 1;                  // n-offset 0 / 16
  const int kh = w >> 1;                   // k-half 0 / 1
  const int nbase = n0 + nsub * 16;

  {  // E/S compute: each block independently (no cross-block dep at all)
    float ev[8], ps8[8];
    float tot = 0.f;
    const int t0 = tid * 8;
#pragma unroll
    for (int j = 0; j < 8; ++j) {
      const float e = expf(v_emb[t0 + j]);
      tot += e; ev[j] = e; ps8[j] = tot;
    }
    float ws = tot;                        // wave-inclusive scan of thread sums
#pragma unroll
    for (int d = 1; d < 64; d <<= 1) {
      float up = __shfl_up(ws, d);
      if (lane >= d) ws += up;
    }
    if (lane == 63) swsum[w] = ws;
    __syncthreads();
    float wbase = 0.f;
#pragma unroll
    for (int k = 0; k < 4; ++k) if (k < w) wbase += swsum[k];
    const float base = wbase + (ws - tot); // exclusive base for this thread
#pragma unroll
    for (int j = 0; j < 8; ++j) {
      const int d = t0 + j;
      sm.g.Sarr[d] = base + ps8[j];
      const unsigned short bv = f2bf(ev[j]);
      sm.g.GL0[d + 127] = bv;              // GL0[i]=E[i-127]
      sm.g.GL1[d + 126] = bv;              // GL1[i]=E[i-126]
    }
    if (tid < 31) sm.g.GL0[96 + tid] = 0;  // zero [96,127)
    if (tid < 30) sm.g.GL1[96 + tid] = 0;  // zero [96,126)
    if (tid == 0) { sm.g.GL0[2175] = 0; sm.g.GL1[2174] = 0; sm.g.GL1[2175] = 0; }
    __syncthreads();
  }
  const float sinv = 1.0f / sm.g.Sarr[nbase + lm];  // keep in reg past red reuse

  bb_wait(flag0b);   // Agr[b] complete (coherent stores acked at IC)

  {
    const unsigned long long* __restrict__ abase64 =
        (const unsigned long long*)(Agr + (size_t)b * 256 * 64 * 8);
    const int sbase = nbase + lm - 1920;
    const int kstart = 2048 - (n0 + 32);   // multiple of 32
    const int iters = bn + 1;              // total 32-k steps for this tile

    f32x4 acc[4];
#pragma unroll
    for (int mt = 0; mt < 4; ++mt) acc[mt] = (f32x4){0.f, 0.f, 0.f, 0.f};

    union AF { unsigned long long q[2]; bf16x8 v; };
    union BF { unsigned int u[4]; bf16x8 v; };
    AF a[3][4];
    BF bb[3];

#define LOAD_FRAGS(J_, SL) do {                                             \
    const int k_ = kstart + (kh + 2 * (J_)) * 32;                           \
    const int kq8_ = (k_ >> 3) + quad;                                      \
    const unsigned long long* ab_ = abase64 + (size_t)(kq8_ * 64 + lm) * 2; \
    a[SL][0].q[0] = __hip_atomic_load(ab_ +  0, __ATOMIC_RELAXED, __HIP_MEMORY_SCOPE_AGENT); \
    a[SL][0].q[1] = __hip_atomic_load(ab_ +  1, __ATOMIC_RELAXED, __HIP_MEMORY_SCOPE_AGENT); \
    a[SL][1].q[0] = __hip_atomic_load(ab_ + 32, __ATOMIC_RELAXED, __HIP_MEMORY_SCOPE_AGENT); \
    a[SL][1].q[1] = __hip_atomic_load(ab_ + 33, __ATOMIC_RELAXED, __HIP_MEMORY_SCOPE_AGENT); \
    a[SL][2].q[0] = __hip_atomic_load(ab_ + 64, __ATOMIC_RELAXED, __HIP_MEMORY_SCOPE_AGENT); \
    a[SL][2].q[1] = __hip_atomic_load(ab_ + 65, __ATOMIC_RELAXED, __HIP_MEMORY_SCOPE_AGENT); \
    a[SL][3].q[0] = __hip_atomic_load(ab_ + 96, __ATOMIC_RELAXED, __HIP_MEMORY_SCOPE_AGENT); \
    a[SL][3].q[1] = __hip_atomic_load(ab_ + 97, __ATOMIC_RELAXED, __HIP_MEMORY_SCOPE_AGENT); \
    const int s_ = sbase + k_ + quad * 8;                                   \
    const unsigned int* gb_ = (s_ & 1) ? (const unsigned int*)sm.g.GL1      \
                                       : (const unsigned int*)sm.g.GL0;     \
    const int off_ = s_ >> 1;                                               \
    bb[SL].u[0] = gb_[off_ + 0]; bb[SL].u[1] = gb_[off_ + 1];               \
    bb[SL].u[2] = gb_[off_ + 2]; bb[SL].u[3] = gb_[off_ + 3];               \
  } while (0)

#define MFMA4(SL) do {                                                      \
    acc[0] = __builtin_amdgcn_mfma_f32_16x16x32_bf16(a[SL][0].v, bb[SL].v, acc[0], 0, 0, 0); \
    acc[1] = __builtin_amdgcn_mfma_f32_16x16x32_bf16(a[SL][1].v, bb[SL].v, acc[1], 0, 0, 0); \
    acc[2] = __builtin_amdgcn_mfma_f32_16x16x32_bf16(a[SL][2].v, bb[SL].v, acc[2], 0, 0, 0); \
    acc[3] = __builtin_amdgcn_mfma_f32_16x16x32_bf16(a[SL][3].v, bb[SL].v, acc[3], 0, 0, 0); \
  } while (0)

    const int J = (iters > kh) ? ((iters - kh + 1) >> 1) : 0;  // wave-iters
    if (J > 0) {
      LOAD_FRAGS(0, 0);
      if (J > 1) LOAD_FRAGS(1, 1);
      int j = 0;
      while (true) {
        if (j + 2 < J) LOAD_FRAGS(j + 2, 2);
        MFMA4(0);
        if (++j >= J) break;
        if (j + 2 < J) LOAD_FRAGS(j + 2, 0);
        MFMA4(1);
        if (++j >= J) break;
        if (j + 2 < J) LOAD_FRAGS(j + 2, 1);
        MFMA4(2);
        if (++j >= J) break;
      }
    }
#undef LOAD_FRAGS
#undef MFMA4

    // reduce k-half 1 into k-half 0 via LDS (lane-contiguous, conflict-free)
    if (kh == 1) {
      float (*rd)[64] = nsub ? sm.g.red2 : sm.g.red;
#pragma unroll
      for (int mt = 0; mt < 4; ++mt)
#pragma unroll
        for (int r = 0; r < 4; ++r) rd[mt * 4 + r][lane] = acc[mt][r];
    }
    __syncthreads();
    if (kh == 0) {
      float (*rd)[64] = nsub ? sm.g.red2 : sm.g.red;
#pragma unroll
      for (int mt = 0; mt < 4; ++mt)
#pragma unroll
        for (int r = 0; r < 4; ++r) acc[mt][r] += rd[mt * 4 + r][lane];

      // epilogue: C/D layout col(s)=lm, row(c)=quad*4+r; coherent P stores
#pragma unroll
      for (int mt = 0; mt < 4; ++mt) {
#pragma unroll
        for (int r = 0; r < 4; ++r) {
          const int c = mt * 16 + quad * 4 + r;
          const float val = __expf(acc[mt][r] * sinv);
          __hip_atomic_store(&P[((size_t)(b * 64 + c)) * LSEQ + nbase + lm],
                             val, __ATOMIC_RELAXED, __HIP_MEMORY_SCOPE_AGENT);
        }
      }
    }
  }
  bb_arrive(cnt1b, flag1b);        // P[b] columns from this block complete

  // ---------------- phase 2: chunk-hists + scan + fence-free emission --
  {
    const int c = bid & 63;        // this block's vocab bin; bc = bid
    const int* __restrict__ irow = idx + b * LSEQ;
    int ii[8];
#pragma unroll
    for (int r = 0; r < 8; ++r)    // idx-only loads: overlap the wait
      ii[r] = irow[(w * 8 + r) * 64 + lane];

    bb_wait(flag1b);               // all of batch b's P rows ready

    const float* __restrict__ prow = P + (size_t)bid * LSEQ;
    float p[8];
#pragma unroll
    for (int r = 0; r < 8; ++r)    // coherent sc1 loads (single-use stream)
      p[r] = __hip_atomic_load(prow + (w * 8 + r) * 64 + lane,
                               __ATOMIC_RELAXED, __HIP_MEMORY_SCOPE_AGENT);

    for (int i = tid; i < NC * 65; i += 256) ((float*)sm.s.Hs)[i] = 0.f;
    __syncthreads();
#pragma unroll
    for (int r = 0; r < 8; ++r) atomicAdd(&sm.s.Hs[w * 8 + r][ii[r]], p[r]);
    __syncthreads();

    // exclusive scan across chunks, per bin: 2 bins per pass (lane halves)
    const int hhalf = lane >> 5, l32 = lane & 31;
#pragma unroll
    for (int r = 0; r < 8; ++r) {
      const int v = w * 16 + r * 2 + hhalf;
      const float h = sm.s.Hs[l32][v];
      float x = h;
#pragma unroll
      for (int d = 1; d < 32; d <<= 1) {
        float up = __shfl_up(x, d, 32);
        if (l32 >= d) x += up;
      }
      sm.s.Hs[l32][v] = x - h;     // exclusive
    }
    __syncthreads();

    const float wv = Wv[0];
#pragma unroll
    for (int r = 0; r < 8; ++r) {
      const int ch = w * 8 + r;
      unsigned long long em = __ballot(ii[r] == c);   // emission points
      if (em == 0ull) continue;                       // wave-uniform skip
      // per-chunk setup (wave-synchronous LDS, no fences):
      sm.s.pl[w][lane] = p[r];                        // stage p
      sm.s.mk[w][lane] = 0ull;
      atomicOr(&sm.s.mk[w][ii[r]], 1ull << lane);     // bin <- source lanes
      float ps = p[r];                                // within-chunk prefix
#pragma unroll
      for (int d = 1; d < 64; d <<= 1) {
        float up = __shfl_up(ps, d);
        if (lane >= d) ps += up;
      }
      const float hbase = sm.s.Hs[ch][lane];
      float zex = hbase;                              // Z_excl = sum_v Hs
#pragma unroll
      for (int d = 1; d < 64; d <<= 1) zex += __shfl_xor(zex, d);
      const unsigned long long myMask = sm.s.mk[w][lane];
      while (em) {
        const int srel = __builtin_ctzll(em);
        em &= em - 1;
        unsigned long long mm = myMask &
            ((srel == 63) ? ~0ull : ((1ull << (srel + 1)) - 1ull));
        float B = hbase;                              // bin value at this t
        while (mm) { const int l = __builtin_ctzll(mm); mm &= mm - 1; B += sm.s.pl[w][l]; }
        const float z = zex + __shfl(ps, srel);       // denominator
        out[((size_t)(b * LSEQ + ch * 64 + srel)) * 64 + lane] = wv * B / z;
      }
    }
  }
}

extern "C" void kernel_launch(void* const* d_in, const int* in_sizes, int n_in,
                              void* d_out, int out_size, void* d_ws, size_t ws_size,
                              hipStream_t stream) {
  const int* idx     = (const int*)d_in[0];     // [16, 2048]
  const float* Wq    = (const float*)d_in[1];   // [64, 64]
  const float* Wv    = (const float*)d_in[2];   // [64, 64] (only [0,0] used)
  const float* v_emb = (const float*)d_in[3];   // [2048, 1]
  float* out = (float*)d_out;                   // [16, 2048, 64] fp32

  // workspace: S/Ebf slots retained for layout compat | P[1024*2048] f32 |
  // Agr[16*256*64*8] bf16 | sync region at +16MB (128B lines)
  float* S = (float*)d_ws;
  float* P = S + LSEQ;
  unsigned short* Ebf = (unsigned short*)(P + (size_t)NB * NV * LSEQ);
  unsigned short* Agr = Ebf + LSEQ;
  unsigned int* bar = (unsigned int*)((char*)d_ws + (16u << 20));

  hipMemsetAsync(bar, 0, 8192, stream);   // zero all cnt/flag lines

  // Plain launch: all 1024 blocks co-resident by capacity (4/CU exactly;
  // VGPR/LDS allow >=6/CU), so the inter-block spin barriers cannot deadlock.
  k_fused<<<dim3(NBLK), dim3(256), 0, stream>>>(idx, Wq, Wv, v_emb, Agr, P,
                                                out, bar);
}

// Round 9
// 118.524 us; speedup vs baseline: 1.8578x; 1.0380x over previous
//
#include <hip/hip_runtime.h>

// B=16, L=2048, V=64.
// Algebraic reduction (e is one-hot):
//   E[d] = exp(v_emb[d]); S[t] = prefix_sum(E)[t]
//   F[b,c,s] = sum_{k<=s} E[s-k] * Wq[idx[b,k], c]            (causal Toeplitz GEMM)
//   P[b,c,s] = exp(F[b,c,s] / S[s])                           (softmax w/o max; scores tiny)
//   out[b,t,v] = Wv00 * (sum_{s<=t, idx[b,s]==v} P[b,c_t,s]) / (sum_{s<=t} P[b,c_t,s]),  c_t = idx[b,t]
//
// R24: R23 hit 123us total (plain launch cut ~28us of cooperative-launch
// overhead; k_fused steady at 63us vs ~12us busy). The idle: phase0 gather +
// barrier0 + GEMM A-loads through sc1 (L2-bypass, IC latency ~600-900cyc,
// 136MB of 33x-reuse traffic uncached). Fix: GEMM goes block-local. Wq is
// 16KB -> stage bf16 Wq[64][65] + reversed-idx row offsets ro_u16[2048]
// (=idx[2047-i]*65) + E/S in LDS; build A-fragments from LDS (1 ds_read_b128
// ro + 32 ds_read_u16 per K-step; quad-broadcast ro; odd stride pads banks).
// Phase0/barrier0/Agr deleted. Single remaining sync: P barrier (transpose),
// zero-fence sc1 as verified in R22/R23. LDS 29.5KB -> 4 blocks/CU.
// Predicted k_fused 63 -> 28-38us, total -> 95-108.

#define LSEQ 2048
#define NB 16
#define NV 64
#define NC 32             // 32 chunks of 64
#define NBLK 1024         // fused grid size
#define BPB 64            // blocks per batch

typedef __attribute__((ext_vector_type(8))) short bf16x8;
typedef __attribute__((ext_vector_type(4))) float f32x4;

__device__ __forceinline__ unsigned short f2bf(float f) {   // RNE float->bf16
  unsigned int u = __float_as_uint(f);
  return (unsigned short)((u + 0x7FFFu + ((u >> 16) & 1u)) >> 16);
}

// ---- per-batch barrier, FENCE-FREE (verified R22/R23) -------------------
__device__ __forceinline__ void bb_arrive(unsigned int* cnt, unsigned int* flag) {
  __syncthreads();
  if (threadIdx.x == 0) {
    unsigned int old = __hip_atomic_fetch_add(cnt, 1u, __ATOMIC_RELAXED,
                                              __HIP_MEMORY_SCOPE_AGENT);
    if (old == BPB - 1u)
      __hip_atomic_store(flag, 1u, __ATOMIC_RELAXED, __HIP_MEMORY_SCOPE_AGENT);
  }
}
__device__ __forceinline__ void bb_wait(unsigned int* flag) {
  if (threadIdx.x == 0) {
    while (__hip_atomic_load(flag, __ATOMIC_RELAXED,
                             __HIP_MEMORY_SCOPE_AGENT) == 0u)
      __builtin_amdgcn_s_sleep(2);
  }
  __syncthreads();
}

// =====================================================================
// Fused kernel, grid=1024, plain launch (4 blocks/CU by capacity):
// setup (Wq/ro/E/S in LDS) | GEMM 1 tile/block (all block-local) |
// P sc1 store | batchbar | phase2 scan+emit (1 (b,c)/block).
// =====================================================================
__global__ __launch_bounds__(256, 4) void k_fused(
    const int* __restrict__ idx, const float* __restrict__ Wq,
    const float* __restrict__ Wv, const float* __restrict__ v_emb,
    float* __restrict__ P, float* __restrict__ out,
    unsigned int* __restrict__ bar) {
  union SMem {
    struct {  // phase 1 (setup + GEMM)
      unsigned short Wqb[64 * 65];  // bf16 Wq, padded rows (8320B)
      unsigned short ro[2048];      // ro[i] = idx[b,2047-i]*65 (4096B)
      unsigned short GL0[2208];     // GL0[i] = (127<=i<2175) ? E[i-127] : 0
      unsigned short GL1[2176];     // GL1[i] = GLv(i+1)
      float red[16][64];
      float red2[16][64];
      float Spart[32];              // S[n0..n0+32) for this block's tile
      float swsum[4];
    } g;
    struct {  // phase 2 (scan+emit)
      float Hs[NC][65];
      float pl[4][64];
      unsigned long long mk[4][64];
    } s;
  };
  __shared__ SMem sm;

  const int bid = blockIdx.x;     // [0, 1024)
  const int tid = threadIdx.x;
  const int w = tid >> 6;
  const int lane = tid & 63;
  const int b = bid >> 6;         // this block's batch, ALL phases

  // sync layout in bar (uints; 32 uints = one 128B line each):
  // cnt[b] @b*32 | flag[b] @512+b*32
  unsigned int* cntb  = bar +   0 + b * 32;
  unsigned int* flagb = bar + 512 + b * 32;

  const int bn = 63 - (bid & 63);          // heavy (long-K) blocks first
  const int n0 = bn * 32;
  const int quad = lane >> 4;
  const int lm = lane & 15;
  const int nsub = w & 1;                  // n-offset 0 / 16
  const int kh = w >> 1;                   // k-half 0 / 1
  const int nbase = n0 + nsub * 16;

  // ---------------- setup: Wq -> LDS bf16, ro, E/S --------------------
  {
    // Wq staging: coalesced fp32 read, bf16 padded store
#pragma unroll
    for (int u = 0; u < 16; ++u) {
      const int e = tid * 16 + u;          // [0,4096)
      sm.g.Wqb[(e >> 6) * 65 + (e & 63)] = f2bf(Wq[e]);
    }
    // reversed-index row offsets (coalesced idx read, reversed LDS write)
#pragma unroll
    for (int j = 0; j < 8; ++j) {
      const int t = tid * 8 + j;
      sm.g.ro[2047 - t] = (unsigned short)(idx[b * LSEQ + t] * 65);
    }
    // E/S: block-local compute (R23-verified scan), Spart instead of Sarr
    float ev[8], ps8[8];
    float tot = 0.f;
    const int t0 = tid * 8;
#pragma unroll
    for (int j = 0; j < 8; ++j) {
      const float e = expf(v_emb[t0 + j]);
      tot += e; ev[j] = e; ps8[j] = tot;
    }
    float ws = tot;                        // wave-inclusive scan of thread sums
#pragma unroll
    for (int d = 1; d < 64; d <<= 1) {
      float up = __shfl_up(ws, d);
      if (lane >= d) ws += up;
    }
    if (lane == 63) sm.g.swsum[w] = ws;
    __syncthreads();
    float wbase = 0.f;
#pragma unroll
    for (int k = 0; k < 4; ++k) if (k < w) wbase += sm.g.swsum[k];
    const float base = wbase + (ws - tot); // exclusive base for this thread
#pragma unroll
    for (int j = 0; j < 8; ++j) {
      const int d = t0 + j;
      const float Sv = base + ps8[j];
      if ((unsigned)(d - n0) < 32u) sm.g.Spart[d - n0] = Sv;
      const unsigned short bv = f2bf(ev[j]);
      sm.g.GL0[d + 127] = bv;              // GL0[i]=E[i-127]
      sm.g.GL1[d + 126] = bv;              // GL1[i]=E[i-126]
    }
    if (tid < 31) sm.g.GL0[96 + tid] = 0;  // zero [96,127)
    if (tid < 30) sm.g.GL1[96 + tid] = 0;  // zero [96,126)
    if (tid == 0) { sm.g.GL0[2175] = 0; sm.g.GL1[2174] = 0; sm.g.GL1[2175] = 0; }
    __syncthreads();                       // all LDS (Wqb/ro/GL/Spart) ready
  }
  const float sinv = 1.0f / sm.g.Spart[nsub * 16 + lm];

  // ---------------- phase 1: MFMA GEMM, fully block-local -------------
  {
    const int sbase = nbase + lm - 1920;
    const int kstart = 2048 - (n0 + 32);   // multiple of 32
    const int iters = bn + 1;              // total 32-k steps for this tile

    f32x4 acc[4];
#pragma unroll
    for (int mt = 0; mt < 4; ++mt) acc[mt] = (f32x4){0.f, 0.f, 0.f, 0.f};

    union AF { unsigned short s[8]; bf16x8 v; };
    union BF { unsigned int u[4]; bf16x8 v; };
    AF a[3][4];
    BF bb[3];

// A-fragment built from LDS: ro_b128 (quad-broadcast) + 32x ds_read_u16.
// a[SL][mt].s[j] = Wqb[ ro[k_+quad*8+j] + mt*16 + lm ]  (== old Agr value)
#define LOAD_FRAGS(J_, SL) do {                                             \
    const int k_ = kstart + (kh + 2 * (J_)) * 32;                           \
    const int i0_ = k_ + quad * 8;                                          \
    unsigned short ro_[8];                                                  \
    *(uint4*)ro_ = *(const uint4*)&sm.g.ro[i0_];                            \
_Pragma("unroll")                                                           \
    for (int j_ = 0; j_ < 8; ++j_) {                                        \
      const int base_ = (int)ro_[j_] + lm;                                  \
      a[SL][0].s[j_] = sm.g.Wqb[base_ +  0];                                \
      a[SL][1].s[j_] = sm.g.Wqb[base_ + 16];                                \
      a[SL][2].s[j_] = sm.g.Wqb[base_ + 32];                                \
      a[SL][3].s[j_] = sm.g.Wqb[base_ + 48];                                \
    }                                                                       \
    const int s_ = sbase + k_ + quad * 8;                                   \
    const unsigned int* gb_ = (s_ & 1) ? (const unsigned int*)sm.g.GL1      \
                                       : (const unsigned int*)sm.g.GL0;     \
    const int off_ = s_ >> 1;                                               \
    bb[SL].u[0] = gb_[off_ + 0]; bb[SL].u[1] = gb_[off_ + 1];               \
    bb[SL].u[2] = gb_[off_ + 2]; bb[SL].u[3] = gb_[off_ + 3];               \
  } while (0)

#define MFMA4(SL) do {                                                      \
    acc[0] = __builtin_amdgcn_mfma_f32_16x16x32_bf16(a[SL][0].v, bb[SL].v, acc[0], 0, 0, 0); \
    acc[1] = __builtin_amdgcn_mfma_f32_16x16x32_bf16(a[SL][1].v, bb[SL].v, acc[1], 0, 0, 0); \
    acc[2] = __builtin_amdgcn_mfma_f32_16x16x32_bf16(a[SL][2].v, bb[SL].v, acc[2], 0, 0, 0); \
    acc[3] = __builtin_amdgcn_mfma_f32_16x16x32_bf16(a[SL][3].v, bb[SL].v, acc[3], 0, 0, 0); \
  } while (0)

    const int J = (iters > kh) ? ((iters - kh + 1) >> 1) : 0;  // wave-iters
    if (J > 0) {
      LOAD_FRAGS(0, 0);
      if (J > 1) LOAD_FRAGS(1, 1);
      int j = 0;
      while (true) {
        if (j + 2 < J) LOAD_FRAGS(j + 2, 2);
        MFMA4(0);
        if (++j >= J) break;
        if (j + 2 < J) LOAD_FRAGS(j + 2, 0);
        MFMA4(1);
        if (++j >= J) break;
        if (j + 2 < J) LOAD_FRAGS(j + 2, 1);
        MFMA4(2);
        if (++j >= J) break;
      }
    }
#undef LOAD_FRAGS
#undef MFMA4

    // reduce k-half 1 into k-half 0 via LDS (lane-contiguous, conflict-free)
    if (kh == 1) {
      float (*rd)[64] = nsub ? sm.g.red2 : sm.g.red;
#pragma unroll
      for (int mt = 0; mt < 4; ++mt)
#pragma unroll
        for (int r = 0; r < 4; ++r) rd[mt * 4 + r][lane] = acc[mt][r];
    }
    __syncthreads();
    if (kh == 0) {
      float (*rd)[64] = nsub ? sm.g.red2 : sm.g.red;
#pragma unroll
      for (int mt = 0; mt < 4; ++mt)
#pragma unroll
        for (int r = 0; r < 4; ++r) acc[mt][r] += rd[mt * 4 + r][lane];

      // epilogue: C/D layout col(s)=lm, row(c)=quad*4+r; coherent P stores
#pragma unroll
      for (int mt = 0; mt < 4; ++mt) {
#pragma unroll
        for (int r = 0; r < 4; ++r) {
          const int c = mt * 16 + quad * 4 + r;
          const float val = __expf(acc[mt][r] * sinv);
          __hip_atomic_store(&P[((size_t)(b * 64 + c)) * LSEQ + nbase + lm],
                             val, __ATOMIC_RELAXED, __HIP_MEMORY_SCOPE_AGENT);
        }
      }
    }
  }
  bb_arrive(cntb, flagb);          // P[b] columns from this block complete

  // ---------------- phase 2: chunk-hists + scan + fence-free emission --
  {
    const int c = bid & 63;        // this block's vocab bin; bc = bid
    const int* __restrict__ irow = idx + b * LSEQ;
    int ii[8];
#pragma unroll
    for (int r = 0; r < 8; ++r)    // idx-only loads: overlap the wait
      ii[r] = irow[(w * 8 + r) * 64 + lane];

    bb_wait(flagb);                // all of batch b's P rows ready

    const float* __restrict__ prow = P + (size_t)bid * LSEQ;
    float p[8];
#pragma unroll
    for (int r = 0; r < 8; ++r)    // coherent sc1 loads (single-use stream)
      p[r] = __hip_atomic_load(prow + (w * 8 + r) * 64 + lane,
                               __ATOMIC_RELAXED, __HIP_MEMORY_SCOPE_AGENT);

    for (int i = tid; i < NC * 65; i += 256) ((float*)sm.s.Hs)[i] = 0.f;
    __syncthreads();
#pragma unroll
    for (int r = 0; r < 8; ++r) atomicAdd(&sm.s.Hs[w * 8 + r][ii[r]], p[r]);
    __syncthreads();

    // exclusive scan across chunks, per bin: 2 bins per pass (lane halves)
    const int hhalf = lane >> 5, l32 = lane & 31;
#pragma unroll
    for (int r = 0; r < 8; ++r) {
      const int v = w * 16 + r * 2 + hhalf;
      const float h = sm.s.Hs[l32][v];
      float x = h;
#pragma unroll
      for (int d = 1; d < 32; d <<= 1) {
        float up = __shfl_up(x, d, 32);
        if (l32 >= d) x += up;
      }
      sm.s.Hs[l32][v] = x - h;     // exclusive
    }
    __syncthreads();

    const float wv = Wv[0];
#pragma unroll
    for (int r = 0; r < 8; ++r) {
      const int ch = w * 8 + r;
      unsigned long long em = __ballot(ii[r] == c);   // emission points
      if (em == 0ull) continue;                       // wave-uniform skip
      // per-chunk setup (wave-synchronous LDS, no fences):
      sm.s.pl[w][lane] = p[r];                        // stage p
      sm.s.mk[w][lane] = 0ull;
      atomicOr(&sm.s.mk[w][ii[r]], 1ull << lane);     // bin <- source lanes
      float ps = p[r];                                // within-chunk prefix
#pragma unroll
      for (int d = 1; d < 64; d <<= 1) {
        float up = __shfl_up(ps, d);
        if (lane >= d) ps += up;
      }
      const float hbase = sm.s.Hs[ch][lane];
      float zex = hbase;                              // Z_excl = sum_v Hs
#pragma unroll
      for (int d = 1; d < 64; d <<= 1) zex += __shfl_xor(zex, d);
      const unsigned long long myMask = sm.s.mk[w][lane];
      while (em) {
        const int srel = __builtin_ctzll(em);
        em &= em - 1;
        unsigned long long mm = myMask &
            ((srel == 63) ? ~0ull : ((1ull << (srel + 1)) - 1ull));
        float B = hbase;                              // bin value at this t
        while (mm) { const int l = __builtin_ctzll(mm); mm &= mm - 1; B += sm.s.pl[w][l]; }
        const float z = zex + __shfl(ps, srel);       // denominator
        out[((size_t)(b * LSEQ + ch * 64 + srel)) * 64 + lane] = wv * B / z;
      }
    }
  }
}

extern "C" void kernel_launch(void* const* d_in, const int* in_sizes, int n_in,
                              void* d_out, int out_size, void* d_ws, size_t ws_size,
                              hipStream_t stream) {
  const int* idx     = (const int*)d_in[0];     // [16, 2048]
  const float* Wq    = (const float*)d_in[1];   // [64, 64]
  const float* Wv    = (const float*)d_in[2];   // [64, 64] (only [0,0] used)
  const float* v_emb = (const float*)d_in[3];   // [2048, 1]
  float* out = (float*)d_out;                   // [16, 2048, 64] fp32

  // workspace: [2048 f32 pad] | P[1024*2048] f32 | sync region at +16MB
  float* P = (float*)d_ws + LSEQ;
  unsigned int* bar = (unsigned int*)((char*)d_ws + (16u << 20));

  hipMemsetAsync(bar, 0, 8192, stream);   // zero cnt/flag lines

  // Plain launch: 1024 blocks = 4/CU exactly (capacity >=5/CU by LDS, VGPR
  // capped by launch_bounds), so the single spin barrier cannot deadlock.
  k_fused<<<dim3(NBLK), dim3(256), 0, stream>>>(idx, Wq, Wv, v_emb, P, out,
                                                bar);
}

// Round 10
// 117.488 us; speedup vs baseline: 1.8742x; 1.0088x over previous
//
#include <hip/hip_runtime.h>

// B=16, L=2048, V=64.
// Algebraic reduction (e is one-hot):
//   E[d] = exp(v_emb[d]); S[t] = prefix_sum(E)[t]
//   F[b,c,s] = sum_{k<=s} E[s-k] * Wq[idx[b,k], c]            (causal Toeplitz GEMM)
//   P[b,c,s] = exp(F[b,c,s] / S[s])                           (softmax w/o max; scores tiny)
//   out[b,t,v] = Wv00 * (sum_{s<=t, idx[b,s]==v} P[b,c_t,s]) / (sum_{s<=t} P[b,c_t,s]),  c_t = idx[b,t]
//
// R25: R24 hit 118.5 (new best) but: (1) one rocprof replay dispatch took
// 31ms — near-deadlock: grid 1024 at EXACT 4/CU capacity + in-kernel spin
// barrier is fragile; (2) steady k_fused 59us vs 12us busy — blocks occupy
// CUs while spinning for the slowest (bn=63) tile and hold 29.7KB dead LDS
// in phase 2. Fix: replace the last cross-block sync with the HW kernel
// boundary. K1 = setup+GEMM+P (block-local LDS A-path from R24, NORMAL
// L2-cached P stores, no atomics/barriers, blocks retire). K2 = scan+emit
// (normal P loads, boundary flush -> IC hits). No bar, no memset, no sc1,
// no co-residency requirement. Predicted: k1 10-18us, k2 6-12us, total
// 118.5 -> 95-105, no ms-scale outliers.

#define LSEQ 2048
#define NB 16
#define NV 64
#define NC 32             // 32 chunks of 64
#define NBLK 1024

typedef __attribute__((ext_vector_type(8))) short bf16x8;
typedef __attribute__((ext_vector_type(4))) float f32x4;

__device__ __forceinline__ unsigned short f2bf(float f) {   // RNE float->bf16
  unsigned int u = __float_as_uint(f);
  return (unsigned short)((u + 0x7FFFu + ((u >> 16) & 1u)) >> 16);
}

// =====================================================================
// K1: setup (Wq/ro/E/S in LDS) + causal-Toeplitz MFMA GEMM, 1 32-col
// tile per block. All inputs block-local; normal (L2-cached) P stores.
// =====================================================================
__global__ __launch_bounds__(256, 4) void k_gemm(
    const int* __restrict__ idx, const float* __restrict__ Wq,
    const float* __restrict__ v_emb, float* __restrict__ P) {
  struct SMem {
    unsigned short Wqb[64 * 65];  // bf16 Wq, padded rows (8320B)
    unsigned short ro[2048];      // ro[i] = idx[b,2047-i]*65 (4096B)
    unsigned short GL0[2208];     // GL0[i] = (127<=i<2175) ? E[i-127] : 0
    unsigned short GL1[2176];     // GL1[i] = GLv(i+1)
    float red[16][64];
    float red2[16][64];
    float Spart[32];              // S[n0..n0+32) for this block's tile
    float swsum[4];
  };
  __shared__ SMem sm;

  const int bid = blockIdx.x;     // [0, 1024)
  const int tid = threadIdx.x;
  const int w = tid >> 6;
  const int lane = tid & 63;
  const int b = bid >> 6;

  const int bn = 63 - (bid & 63);          // heavy (long-K) blocks first
  const int n0 = bn * 32;
  const int quad = lane >> 4;
  const int lm = lane & 15;
  const int nsub = w & 1;                  // n-offset 0 / 16
  const int kh = w >> 1;                   // k-half 0 / 1
  const int nbase = n0 + nsub * 16;

  // ---------------- setup: Wq -> LDS bf16, ro, E/S --------------------
  {
#pragma unroll
    for (int u = 0; u < 16; ++u) {
      const int e = tid * 16 + u;          // [0,4096)
      sm.Wqb[(e >> 6) * 65 + (e & 63)] = f2bf(Wq[e]);
    }
#pragma unroll
    for (int j = 0; j < 8; ++j) {
      const int t = tid * 8 + j;
      sm.ro[2047 - t] = (unsigned short)(idx[b * LSEQ + t] * 65);
    }
    float ev[8], ps8[8];
    float tot = 0.f;
    const int t0 = tid * 8;
#pragma unroll
    for (int j = 0; j < 8; ++j) {
      const float e = expf(v_emb[t0 + j]);
      tot += e; ev[j] = e; ps8[j] = tot;
    }
    float ws = tot;                        // wave-inclusive scan of thread sums
#pragma unroll
    for (int d = 1; d < 64; d <<= 1) {
      float up = __shfl_up(ws, d);
      if (lane >= d) ws += up;
    }
    if (lane == 63) sm.swsum[w] = ws;
    __syncthreads();
    float wbase = 0.f;
#pragma unroll
    for (int k = 0; k < 4; ++k) if (k < w) wbase += sm.swsum[k];
    const float base = wbase + (ws - tot); // exclusive base for this thread
#pragma unroll
    for (int j = 0; j < 8; ++j) {
      const int d = t0 + j;
      const float Sv = base + ps8[j];
      if ((unsigned)(d - n0) < 32u) sm.Spart[d - n0] = Sv;
      const unsigned short bv = f2bf(ev[j]);
      sm.GL0[d + 127] = bv;                // GL0[i]=E[i-127]
      sm.GL1[d + 126] = bv;                // GL1[i]=E[i-126]
    }
    if (tid < 31) sm.GL0[96 + tid] = 0;    // zero [96,127)
    if (tid < 30) sm.GL1[96 + tid] = 0;    // zero [96,126)
    if (tid == 0) { sm.GL0[2175] = 0; sm.GL1[2174] = 0; sm.GL1[2175] = 0; }
    __syncthreads();                       // all LDS (Wqb/ro/GL/Spart) ready
  }
  const float sinv = 1.0f / sm.Spart[nsub * 16 + lm];

  // ---------------- MFMA GEMM, fully block-local ----------------------
  {
    const int sbase = nbase + lm - 1920;
    const int kstart = 2048 - (n0 + 32);   // multiple of 32
    const int iters = bn + 1;              // total 32-k steps for this tile

    f32x4 acc[4];
#pragma unroll
    for (int mt = 0; mt < 4; ++mt) acc[mt] = (f32x4){0.f, 0.f, 0.f, 0.f};

    union AF { unsigned short s[8]; bf16x8 v; };
    union BF { unsigned int u[4]; bf16x8 v; };
    AF a[3][4];
    BF bb[3];

// A-fragment from LDS: ro_b128 (quad-broadcast) + 32x ds_read_u16.
// a[SL][mt].s[j] = Wqb[ ro[k_+quad*8+j] + mt*16 + lm ]
#define LOAD_FRAGS(J_, SL) do {                                             \
    const int k_ = kstart + (kh + 2 * (J_)) * 32;                           \
    const int i0_ = k_ + quad * 8;                                          \
    unsigned short ro_[8];                                                  \
    *(uint4*)ro_ = *(const uint4*)&sm.ro[i0_];                              \
_Pragma("unroll")                                                           \
    for (int j_ = 0; j_ < 8; ++j_) {                                        \
      const int base_ = (int)ro_[j_] + lm;                                  \
      a[SL][0].s[j_] = sm.Wqb[base_ +  0];                                  \
      a[SL][1].s[j_] = sm.Wqb[base_ + 16];                                  \
      a[SL][2].s[j_] = sm.Wqb[base_ + 32];                                  \
      a[SL][3].s[j_] = sm.Wqb[base_ + 48];                                  \
    }                                                                       \
    const int s_ = sbase + k_ + quad * 8;                                   \
    const unsigned int* gb_ = (s_ & 1) ? (const unsigned int*)sm.GL1        \
                                       : (const unsigned int*)sm.GL0;       \
    const int off_ = s_ >> 1;                                               \
    bb[SL].u[0] = gb_[off_ + 0]; bb[SL].u[1] = gb_[off_ + 1];               \
    bb[SL].u[2] = gb_[off_ + 2]; bb[SL].u[3] = gb_[off_ + 3];               \
  } while (0)

#define MFMA4(SL) do {                                                      \
    acc[0] = __builtin_amdgcn_mfma_f32_16x16x32_bf16(a[SL][0].v, bb[SL].v, acc[0], 0, 0, 0); \
    acc[1] = __builtin_amdgcn_mfma_f32_16x16x32_bf16(a[SL][1].v, bb[SL].v, acc[1], 0, 0, 0); \
    acc[2] = __builtin_amdgcn_mfma_f32_16x16x32_bf16(a[SL][2].v, bb[SL].v, acc[2], 0, 0, 0); \
    acc[3] = __builtin_amdgcn_mfma_f32_16x16x32_bf16(a[SL][3].v, bb[SL].v, acc[3], 0, 0, 0); \
  } while (0)

    const int J = (iters > kh) ? ((iters - kh + 1) >> 1) : 0;  // wave-iters
    if (J > 0) {
      LOAD_FRAGS(0, 0);
      if (J > 1) LOAD_FRAGS(1, 1);
      int j = 0;
      while (true) {
        if (j + 2 < J) LOAD_FRAGS(j + 2, 2);
        MFMA4(0);
        if (++j >= J) break;
        if (j + 2 < J) LOAD_FRAGS(j + 2, 0);
        MFMA4(1);
        if (++j >= J) break;
        if (j + 2 < J) LOAD_FRAGS(j + 2, 1);
        MFMA4(2);
        if (++j >= J) break;
      }
    }
#undef LOAD_FRAGS
#undef MFMA4

    // reduce k-half 1 into k-half 0 via LDS (lane-contiguous, conflict-free)
    if (kh == 1) {
      float (*rd)[64] = nsub ? sm.red2 : sm.red;
#pragma unroll
      for (int mt = 0; mt < 4; ++mt)
#pragma unroll
        for (int r = 0; r < 4; ++r) rd[mt * 4 + r][lane] = acc[mt][r];
    }
    __syncthreads();
    if (kh == 0) {
      float (*rd)[64] = nsub ? sm.red2 : sm.red;
#pragma unroll
      for (int mt = 0; mt < 4; ++mt)
#pragma unroll
        for (int r = 0; r < 4; ++r) acc[mt][r] += rd[mt * 4 + r][lane];

      // epilogue: C/D layout col(s)=lm, row(c)=quad*4+r; NORMAL stores
#pragma unroll
      for (int mt = 0; mt < 4; ++mt) {
#pragma unroll
        for (int r = 0; r < 4; ++r) {
          const int c = mt * 16 + quad * 4 + r;
          P[((size_t)(b * 64 + c)) * LSEQ + nbase + lm] = __expf(acc[mt][r] * sinv);
        }
      }
    }
  }
}

// =====================================================================
// K2: chunk-hists + scan + fence-free emission, 1 (b,c) per block.
// P visible via the kernel boundary (driver cache maintenance); reads
// served from Infinity Cache.
// =====================================================================
__global__ __launch_bounds__(256, 8) void k_scanemit(
    const int* __restrict__ idx, const float* __restrict__ P,
    const float* __restrict__ Wv, float* __restrict__ out) {
  __shared__ float Hs[NC][65];
  __shared__ float pl[4][64];
  __shared__ unsigned long long mk[4][64];

  const int bc = blockIdx.x;      // [0, 1024)
  const int b = bc >> 6;
  const int c = bc & 63;
  const int w = threadIdx.x >> 6;
  const int lane = threadIdx.x & 63;
  const int tid = threadIdx.x;

  const float* __restrict__ prow = P + (size_t)bc * LSEQ;
  const int* __restrict__ irow = idx + b * LSEQ;

  float p[8]; int ii[8];
#pragma unroll
  for (int r = 0; r < 8; ++r) {           // 16 independent coalesced loads
    const int ch = w * 8 + r;
    p[r] = prow[ch * 64 + lane];
    ii[r] = irow[ch * 64 + lane];
  }
  for (int i = tid; i < NC * 65; i += 256) ((float*)Hs)[i] = 0.f;
  __syncthreads();
#pragma unroll
  for (int r = 0; r < 8; ++r) atomicAdd(&Hs[w * 8 + r][ii[r]], p[r]);
  __syncthreads();

  // exclusive scan across chunks, per bin: 2 bins per pass (lane halves)
  const int hhalf = lane >> 5, l32 = lane & 31;
#pragma unroll
  for (int r = 0; r < 8; ++r) {
    const int v = w * 16 + r * 2 + hhalf;
    const float h = Hs[l32][v];
    float x = h;
#pragma unroll
    for (int d = 1; d < 32; d <<= 1) {
      float up = __shfl_up(x, d, 32);
      if (l32 >= d) x += up;
    }
    Hs[l32][v] = x - h;                   // exclusive
  }
  __syncthreads();

  const float wv = Wv[0];
#pragma unroll
  for (int r = 0; r < 8; ++r) {
    const int ch = w * 8 + r;
    unsigned long long em = __ballot(ii[r] == c);   // emission points
    if (em == 0ull) continue;                       // wave-uniform skip
    // per-chunk setup (wave-synchronous LDS, no fences):
    pl[w][lane] = p[r];                             // stage p
    mk[w][lane] = 0ull;
    atomicOr(&mk[w][ii[r]], 1ull << lane);          // bin <- source lanes
    float ps = p[r];                                // within-chunk prefix
#pragma unroll
    for (int d = 1; d < 64; d <<= 1) {
      float up = __shfl_up(ps, d);
      if (lane >= d) ps += up;
    }
    const float hbase = Hs[ch][lane];
    float zex = hbase;                              // Z_excl = sum_v Hs
#pragma unroll
    for (int d = 1; d < 64; d <<= 1) zex += __shfl_xor(zex, d);
    const unsigned long long myMask = mk[w][lane];
    while (em) {
      const int srel = __builtin_ctzll(em);
      em &= em - 1;
      unsigned long long mm = myMask &
          ((srel == 63) ? ~0ull : ((1ull << (srel + 1)) - 1ull));
      float B = hbase;                              // bin value at this t
      while (mm) { const int l = __builtin_ctzll(mm); mm &= mm - 1; B += pl[w][l]; }
      const float z = zex + __shfl(ps, srel);       // denominator
      out[((size_t)(b * LSEQ + ch * 64 + srel)) * 64 + lane] = wv * B / z;
    }
  }
}

extern "C" void kernel_launch(void* const* d_in, const int* in_sizes, int n_in,
                              void* d_out, int out_size, void* d_ws, size_t ws_size,
                              hipStream_t stream) {
  const int* idx     = (const int*)d_in[0];     // [16, 2048]
  const float* Wq    = (const float*)d_in[1];   // [64, 64]
  const float* Wv    = (const float*)d_in[2];   // [64, 64] (only [0,0] used)
  const float* v_emb = (const float*)d_in[3];   // [2048, 1]
  float* out = (float*)d_out;                   // [16, 2048, 64] fp32

  // workspace: [2048 f32 pad] | P[1024*2048] f32
  float* P = (float*)d_ws + LSEQ;

  k_gemm<<<dim3(NBLK), dim3(256), 0, stream>>>(idx, Wq, v_emb, P);
  k_scanemit<<<dim3(NBLK), dim3(256), 0, stream>>>(idx, P, Wv, out);
}